// Round 12
// baseline (468.994 us; speedup 1.0000x reference)
//
#include <hip/hip_runtime.h>
#include <hip/hip_bf16.h>

// NonLocalBlock2D: x[8,256,64,64] fp32
// All-fp16 pipeline, batches in QUADS. gemm1 = 128n x 64m per wave, stores
// E' = exp(f - lmax) fp16 with j-outer/i-inner store order (each 128B Ep line
// completed by 4 consecutive stores -> single writeback). gemm2 = pure fp16
// GEMM, P = E' * sca, partial fp16.
//   k_prep_w  : weights -> wAll fp16 [384][256], Wc fp16 [256][128]
//   k_split_x : transpose x -> xT fp16 [b][n][c]
//   k_proj    : fp16 GEMM 64x64/wave -> th/ph fp16 [b][n][c], gT fp16 [b][c][n]
//   k_gemm1   : E'[bi][n][m] = exp(theta·phi - lmax[rb][m]); lmax/lsum[32][m]
//   k_prep    : cmax/ssum from lmax/lsum; sca[bi][rb][m] fp16; gs fp16 = g*rcp
//   k_gemm2   : partial[bi][kc][n][c] (fp16) = sum_m gs[c][m]·(E'[n][m]*sca)
//   k_reduce  : yT[b][n][c] fp16 = sum_kc partial (fp32 accum)
//   k_conv    : out = Wc·yT + Wb + x   (at HBM BW ceiling)

#define IC   128
#define CIN  256
#define NPOS 4096
#define NB   8

typedef _Float16 f16;
typedef __attribute__((ext_vector_type(8))) _Float16 f16x8;
typedef __attribute__((ext_vector_type(4))) _Float16 f16x4;
typedef __attribute__((ext_vector_type(4))) float f32x4;
typedef __attribute__((ext_vector_type(4))) float fvec4;

#define MFMA16(a, b, c) __builtin_amdgcn_mfma_f32_16x16x32_f16((a), (b), (c), 0, 0, 0)

// ---------------- weight prep: wAll fp16 [384][256], Wc fp16 [256][128] ----------------
__global__ __launch_bounds__(256) void k_prep_w(
    const float* __restrict__ gw, const float* __restrict__ tw, const float* __restrict__ pw,
    const float* __restrict__ Ww, f16* __restrict__ wAll, f16* __restrict__ Wc)
{
    const int idx = (blockIdx.x * 256 + threadIdx.x) * 4;
    if (idx < 384 * 256) {
        const int row = idx >> 8, col = idx & 255;
        const float* src = (row < 128) ? (gw + row * 256)
                         : (row < 256) ? (tw + (row - 128) * 256)
                                       : (pw + (row - 256) * 256);
        fvec4 v = *reinterpret_cast<const fvec4*>(src + col);
        f16x4 o = { (f16)v[0], (f16)v[1], (f16)v[2], (f16)v[3] };
        *reinterpret_cast<f16x4*>(wAll + idx) = o;
    } else {
        const int j = idx - 384 * 256;          // over 256*128
        fvec4 v = *reinterpret_cast<const fvec4*>(Ww + j);
        f16x4 o = { (f16)v[0], (f16)v[1], (f16)v[2], (f16)v[3] };
        *reinterpret_cast<f16x4*>(Wc + j) = o;
    }
}

// ---------------- transpose x: [b][c][n] fp32 -> [b][n][c] fp16 ----------------
__global__ __launch_bounds__(256) void k_split_x(
    const float* __restrict__ x, f16* __restrict__ xT)
{
    __shared__ float tile[64][65];
    const int b  = blockIdx.z;
    const int c0 = blockIdx.y * 64;
    const int n0 = blockIdx.x * 64;
    const int t  = threadIdx.x;
    {
        const int cc = t >> 4, nn = (t & 15) * 4;
        const float* src = x + ((size_t)b * CIN + c0) * NPOS + n0;
#pragma unroll
        for (int p = 0; p < 4; ++p) {
            fvec4 v = *reinterpret_cast<const fvec4*>(src + (size_t)(cc + p * 16) * NPOS + nn);
            tile[cc + p * 16][nn + 0] = v[0];
            tile[cc + p * 16][nn + 1] = v[1];
            tile[cc + p * 16][nn + 2] = v[2];
            tile[cc + p * 16][nn + 3] = v[3];
        }
    }
    __syncthreads();
    {
        const int c4 = (t & 15) * 4, nr = t >> 4;
#pragma unroll
        for (int p = 0; p < 4; ++p) {
            const int n = nr + p * 16;
            f16x4 o = { (f16)tile[c4 + 0][n], (f16)tile[c4 + 1][n],
                        (f16)tile[c4 + 2][n], (f16)tile[c4 + 3][n] };
            *reinterpret_cast<f16x4*>(xT + ((size_t)b * NPOS + n0 + n) * CIN + c0 + c4) = o;
        }
    }
}

// ---------------- projections: fp16 GEMM, 64x64 per wave ----------------
__global__ __launch_bounds__(256) void k_proj(
    const f16* __restrict__ xT, const f16* __restrict__ wAll,
    const float* __restrict__ gb, const float* __restrict__ tb, const float* __restrict__ pb,
    f16* __restrict__ th, f16* __restrict__ ph, f16* __restrict__ gT)
{
    const int w    = threadIdx.x >> 6;
    const int lane = threadIdx.x & 63;
    const int lrow = lane & 15;
    const int kg   = lane >> 4;
    const int b    = blockIdx.z;
    const int c0   = blockIdx.y * 64;              // [0,384)
    const int n0   = blockIdx.x * 256 + w * 64;

    const f16* X = xT + (size_t)b * NPOS * CIN;

    f32x4 acc[4][4] = {};
#pragma unroll
    for (int ks = 0; ks < 8; ++ks) {
        const int k = ks * 32 + kg * 8;
        f16x8 a[4], bv[4];
#pragma unroll
        for (int i = 0; i < 4; ++i) {
            a[i]  = *reinterpret_cast<const f16x8*>(wAll + (size_t)(c0 + i * 16 + lrow) * CIN + k);
            bv[i] = *reinterpret_cast<const f16x8*>(X + (size_t)(n0 + i * 16 + lrow) * CIN + k);
        }
#pragma unroll
        for (int i = 0; i < 4; ++i)
#pragma unroll
            for (int j = 0; j < 4; ++j)
                acc[i][j] = MFMA16(a[i], bv[j], acc[i][j]);
    }
    const int set = c0 >> 7;                 // 0:g 1:theta 2:phi
    if (set == 0) {
#pragma unroll
        for (int i = 0; i < 4; ++i) {
            const int c = c0 + i * 16 + kg * 4;
#pragma unroll
            for (int j = 0; j < 4; ++j) {
                const int n = n0 + j * 16 + lrow;
#pragma unroll
                for (int r = 0; r < 4; ++r)
                    gT[((size_t)b * IC + c + r) * NPOS + n] = (f16)(acc[i][j][r] + gb[c + r]);
            }
        }
    } else {
        const float* Bi = (set == 1) ? tb : pb;
        f16* dst = (set == 1) ? th : ph;
        const int cl0 = (c0 & 127);
#pragma unroll
        for (int i = 0; i < 4; ++i) {
            const int c = cl0 + i * 16 + kg * 4;
#pragma unroll
            for (int j = 0; j < 4; ++j) {
                const int n = n0 + j * 16 + lrow;
                f16x4 o = { (f16)(acc[i][j][0] + Bi[c + 0]), (f16)(acc[i][j][1] + Bi[c + 1]),
                            (f16)(acc[i][j][2] + Bi[c + 2]), (f16)(acc[i][j][3] + Bi[c + 3]) };
                *reinterpret_cast<f16x4*>(dst + ((size_t)b * NPOS + n) * IC + c) = o;
            }
        }
    }
}

// ---- GEMM1 (quad): 128n x 64m per wave, f^T tiles (A=phi rows m, B=theta rows n).
//      Lane holds m = m0+i*16+kg*4+r (i<4), n = n0+j*16+lrow (j<8).
//      Epilogue: pass A = per-i column max; pass B = j-outer/i-inner exp+store
//      (4 consecutive stores complete each 128B Ep line -> single writeback). ----
__global__ __launch_bounds__(256, 2) void k_gemm1(
    const f16* __restrict__ th, const f16* __restrict__ ph,
    f16* __restrict__ Ep, float* __restrict__ lmax, float* __restrict__ lsum, int b0)
{
    const int w    = threadIdx.x >> 6;
    const int lane = threadIdx.x & 63;
    const int lrow = lane & 15;
    const int kg   = lane >> 4;
    const int gwid = blockIdx.x * 4 + w;      // 0..8191
    const int bi   = gwid >> 11;              // 0..3
    const int tid  = gwid & 2047;
    const int n0   = (tid >> 6) * 128;        // 32 n-tiles of 128
    const int m0   = (tid & 63) * 64;         // 64 m-tiles of 64

    const f16* A = ph + (size_t)(b0 + bi) * NPOS * IC;   // rows m
    const f16* B = th + (size_t)(b0 + bi) * NPOS * IC;   // rows n
    f16* eb = Ep + (size_t)bi * NPOS * NPOS;

    f32x4 acc[4][8] = {};
#pragma unroll
    for (int ks = 0; ks < 4; ++ks) {
        const int k = ks * 32 + kg * 8;
        f16x8 a[4], bv[8];
#pragma unroll
        for (int i = 0; i < 4; ++i)
            a[i] = *reinterpret_cast<const f16x8*>(A + (size_t)(m0 + i * 16 + lrow) * IC + k);
#pragma unroll
        for (int j = 0; j < 8; ++j)
            bv[j] = *reinterpret_cast<const f16x8*>(B + (size_t)(n0 + j * 16 + lrow) * IC + k);
#pragma unroll
        for (int i = 0; i < 4; ++i)
#pragma unroll
            for (int j = 0; j < 8; ++j)
                acc[i][j] = MFMA16(a[i], bv[j], acc[i][j]);
    }

    // pass A: per-m column max over this wave's 128 n (in-reg j + shfl lrow)
    f32x4 cm[4];
#pragma unroll
    for (int i = 0; i < 4; ++i)
#pragma unroll
        for (int r = 0; r < 4; ++r) {
            float c = acc[i][0][r];
#pragma unroll
            for (int j = 1; j < 8; ++j)
                c = fmaxf(c, acc[i][j][r]);
            c = fmaxf(c, __shfl_xor(c, 1));
            c = fmaxf(c, __shfl_xor(c, 2));
            c = fmaxf(c, __shfl_xor(c, 4));
            c = fmaxf(c, __shfl_xor(c, 8));
            cm[i][r] = c;
        }

    // pass B: j-outer / i-inner — line-coalesced stores + running sums
    f32x4 s[4] = {};
#pragma unroll
    for (int j = 0; j < 8; ++j) {
        f16* rowp = eb + (size_t)(n0 + j * 16 + lrow) * NPOS + m0 + kg * 4;
#pragma unroll
        for (int i = 0; i < 4; ++i) {
            f16x4 ev;
#pragma unroll
            for (int r = 0; r < 4; ++r) {
                float e = __expf(acc[i][j][r] - cm[i][r]);
                s[i][r] += e;
                ev[r] = (f16)e;
            }
            *reinterpret_cast<f16x4*>(rowp + i * 16) = ev;
        }
    }

    // stats out
    const int rowblk = n0 >> 7;               // 0..31
#pragma unroll
    for (int i = 0; i < 4; ++i)
#pragma unroll
        for (int r = 0; r < 4; ++r) {
            float ss = s[i][r];
            ss += __shfl_xor(ss, 1);
            ss += __shfl_xor(ss, 2);
            ss += __shfl_xor(ss, 4);
            ss += __shfl_xor(ss, 8);
            if (lrow == 0) {
                const size_t off = ((size_t)bi * 32 + rowblk) * NPOS + m0 + i * 16 + kg * 4 + r;
                lmax[off] = cm[i][r];
                lsum[off] = ss;
            }
        }
}

// ---- prep (quad): cmax/ssum over 32 slots; sca fp16; gs = g/ssum ----
__global__ __launch_bounds__(256) void k_prep(
    const float* __restrict__ lmax, const float* __restrict__ lsum,
    const f16* __restrict__ gT, f16* __restrict__ sca, f16* __restrict__ gs, int b0)
{
    const int bi = blockIdx.y;
    const int m  = blockIdx.x * 256 + threadIdx.x;
    const float* lm = lmax + (size_t)bi * 32 * NPOS;
    const float* ls = lsum + (size_t)bi * 32 * NPOS;
    float cm = -3.0e38f;
#pragma unroll 8
    for (int rb = 0; rb < 32; ++rb)
        cm = fmaxf(cm, lm[(size_t)rb * NPOS + m]);
    float s = 0.f;
    f16* scab = sca + (size_t)bi * 32 * NPOS;
#pragma unroll 8
    for (int rb = 0; rb < 32; ++rb) {
        float e = __expf(lm[(size_t)rb * NPOS + m] - cm);
        s += e * ls[(size_t)rb * NPOS + m];
        scab[(size_t)rb * NPOS + m] = (f16)e;
    }
    const float rc = 1.0f / s;
    const f16* gb = gT + (size_t)(b0 + bi) * IC * NPOS;
    f16* gsb = gs + (size_t)bi * IC * NPOS;
#pragma unroll 8
    for (int c = 0; c < IC; ++c)
        gsb[(size_t)c * NPOS + m] = (f16)((float)gb[(size_t)c * NPOS + m] * rc);
}

// ---- GEMM2 (quad): 32n x 128c per wave; P = E'*sca; kc=4; partial fp16 ----
__global__ __launch_bounds__(256) void k_gemm2(
    const f16* __restrict__ Ep, const f16* __restrict__ sca,
    const f16* __restrict__ gs, f16* __restrict__ partial)
{
    const int w    = threadIdx.x >> 6;
    const int lane = threadIdx.x & 63;
    const int lrow = lane & 15;
    const int kg   = lane >> 4;
    const int gwid = blockIdx.x * 4 + w;      // 0..2047
    const int bi   = gwid >> 9;               // 0..3
    const int rest = gwid & 511;
    const int kc   = rest & 3;                // m-chunk of 1024
    const int nb   = rest >> 2;               // 0..127, n-block of 32
    const int n0   = nb * 32;
    const int rb   = n0 >> 7;                 // 128-row stats slot

    const f16* e0row = Ep + (size_t)bi * NPOS * NPOS + (size_t)(n0 + lrow) * NPOS;
    const f16* e1row = e0row + (size_t)16 * NPOS;
    const f16* srow  = sca + ((size_t)bi * 32 + rb) * NPOS;
    const f16* gsb   = gs + (size_t)bi * IC * NPOS;

    f32x4 acc[8][2] = {};
#pragma unroll 2
    for (int ks = 0; ks < 32; ++ks) {
        const int k = kc * 1024 + ks * 32 + kg * 8;
        f16x8 sv = *reinterpret_cast<const f16x8*>(srow + k);
        f16x8 eA = *reinterpret_cast<const f16x8*>(e0row + k) * sv;
        f16x8 eB = *reinterpret_cast<const f16x8*>(e1row + k) * sv;
#pragma unroll
        for (int i = 0; i < 8; ++i) {
            f16x8 a = *reinterpret_cast<const f16x8*>(gsb + (size_t)(i * 16 + lrow) * NPOS + k);
            acc[i][0] = MFMA16(a, eA, acc[i][0]);
            acc[i][1] = MFMA16(a, eB, acc[i][1]);
        }
    }
    f16* pb = partial + ((size_t)bi * 4 + kc) * NPOS * IC;
#pragma unroll
    for (int i = 0; i < 8; ++i)
#pragma unroll
        for (int j = 0; j < 2; ++j) {
            f16x4 o = { (f16)acc[i][j][0], (f16)acc[i][j][1],
                        (f16)acc[i][j][2], (f16)acc[i][j][3] };
            *reinterpret_cast<f16x4*>(pb + (size_t)(n0 + j * 16 + lrow) * IC
                                         + i * 16 + kg * 4) = o;
        }
}

// ---------------- reduce partials (quad, fp16 in / fp32 accum) -> yT fp16 ----------------
__global__ __launch_bounds__(256) void k_reduce(
    const f16* __restrict__ partial, f16* __restrict__ yT, int b0)
{
    const int bi  = blockIdx.y;
    const int idx = blockIdx.x * 256 + threadIdx.x;   // over NPOS*IC/8
    const f16x8* p = reinterpret_cast<const f16x8*>(partial + (size_t)bi * 4 * NPOS * IC);
    float s[8] = {};
#pragma unroll
    for (int kc = 0; kc < 4; ++kc) {
        f16x8 v = p[(size_t)kc * (NPOS * IC / 8) + idx];
#pragma unroll
        for (int k = 0; k < 8; ++k)
            s[k] += (float)v[k];
    }
    f16x8 o;
#pragma unroll
    for (int k = 0; k < 8; ++k)
        o[k] = (f16)s[k];
    *reinterpret_cast<f16x8*>(yT + (size_t)(b0 + bi) * NPOS * IC + (size_t)idx * 8) = o;
}

// ---------------- final conv + residual: 64x64 per wave ----------------
__global__ __launch_bounds__(256) void k_conv(
    const float* __restrict__ x, const f16* __restrict__ Wc, const float* __restrict__ Wb,
    const f16* __restrict__ yT, float* __restrict__ out)
{
    const int w    = threadIdx.x >> 6;
    const int lane = threadIdx.x & 63;
    const int lrow = lane & 15;
    const int kg   = lane >> 4;
    const int gwid = blockIdx.x * 4 + w;      // 0..2047
    const int ob   = gwid & 3;                // o-block of 64
    const int nb   = (gwid >> 2) & 63;        // n-block of 64
    const int b    = gwid >> 8;
    const int o0   = ob * 64;
    const int n0   = nb * 64;

    const f16* Y = yT + (size_t)b * NPOS * IC;
    f32x4 acc[4][4] = {};
#pragma unroll
    for (int ks = 0; ks < 4; ++ks) {
        const int k = ks * 32 + kg * 8;
        f16x8 a[4], bv[4];
#pragma unroll
        for (int i = 0; i < 4; ++i) {
            a[i]  = *reinterpret_cast<const f16x8*>(Wc + (size_t)(o0 + i * 16 + lrow) * IC + k);
            bv[i] = *reinterpret_cast<const f16x8*>(Y + (size_t)(n0 + i * 16 + lrow) * IC + k);
        }
#pragma unroll
        for (int i = 0; i < 4; ++i)
#pragma unroll
            for (int j = 0; j < 4; ++j)
                acc[i][j] = MFMA16(a[i], bv[j], acc[i][j]);
    }
#pragma unroll
    for (int i = 0; i < 4; ++i) {
        const int o = o0 + i * 16 + kg * 4;
#pragma unroll
        for (int j = 0; j < 4; ++j) {
            const int n = n0 + j * 16 + lrow;
#pragma unroll
            for (int r = 0; r < 4; ++r) {
                const size_t off = ((size_t)b * CIN + o + r) * NPOS + n;
                out[off] = acc[i][j][r] + x[off] + Wb[o + r];
            }
        }
    }
}

extern "C" void kernel_launch(void* const* d_in, const int* in_sizes, int n_in,
                              void* d_out, int out_size, void* d_ws, size_t ws_size,
                              hipStream_t stream)
{
    const float* x  = (const float*)d_in[0];
    const float* gw = (const float*)d_in[1];
    const float* gb = (const float*)d_in[2];
    const float* tw = (const float*)d_in[3];
    const float* tb = (const float*)d_in[4];
    const float* pw = (const float*)d_in[5];
    const float* pb = (const float*)d_in[6];
    const float* Ww = (const float*)d_in[7];
    const float* Wb = (const float*)d_in[8];
    float* out = (float*)d_out;

    char* ws = (char*)d_ws;
    size_t off = 0;
    auto alloc = [&](size_t bytes) -> char* {
        char* p = ws + off;
        off += (bytes + 255) & ~(size_t)255;
        return p;
    };
    f16* xT   = (f16*)alloc((size_t)NB * NPOS * CIN * 2);        // 16.8 MB
    f16* wAll = (f16*)alloc((size_t)384 * 256 * 2);
    f16* Wc   = (f16*)alloc((size_t)CIN * IC * 2);
    f16* th   = (f16*)alloc((size_t)NB * NPOS * IC * 2);         // 8.4 MB
    f16* ph   = (f16*)alloc((size_t)NB * NPOS * IC * 2);
    f16* gT   = (f16*)alloc((size_t)NB * NPOS * IC * 2);
    f16* Ep   = (f16*)alloc((size_t)4 * NPOS * NPOS * 2);        // 134 MB (quad)
    float* lmax = (float*)alloc((size_t)4 * 32 * NPOS * 4);      // 2.1 MB
    float* lsum = (float*)alloc((size_t)4 * 32 * NPOS * 4);
    f16* sca  = (f16*)alloc((size_t)4 * 32 * NPOS * 2);          // 1.0 MB
    f16* gs   = (f16*)alloc((size_t)4 * IC * NPOS * 2);          // 4.2 MB
    f16* partial = (f16*)alloc((size_t)4 * 4 * NPOS * IC * 2);   // 16.8 MB (quad)
    f16* yT   = (f16*)alloc((size_t)NB * NPOS * IC * 2);         // 8.4 MB

    k_prep_w<<<128, 256, 0, stream>>>(gw, tw, pw, Ww, wAll, Wc);
    k_split_x<<<dim3(64, 4, 8), 256, 0, stream>>>(x, xT);
    k_proj<<<dim3(16, 6, 8), 256, 0, stream>>>(xT, wAll, gb, tb, pb, th, ph, gT);

    for (int b0 = 0; b0 < NB; b0 += 4) {
        k_gemm1<<<2048, 256, 0, stream>>>(th, ph, Ep, lmax, lsum, b0);
        k_prep<<<dim3(16, 4), 256, 0, stream>>>(lmax, lsum, gT, sca, gs, b0);
        k_gemm2<<<512, 256, 0, stream>>>(Ep, sca, gs, partial);
        k_reduce<<<dim3(256, 4), 256, 0, stream>>>(partial, yT, b0);
    }
    k_conv<<<dim3(512), 256, 0, stream>>>(x, Wc, Wb, yT, out);
}

// Round 13
// 455.797 us; speedup vs baseline: 1.0290x; 1.0290x over previous
//
#include <hip/hip_runtime.h>
#include <hip/hip_bf16.h>

// NonLocalBlock2D: x[8,256,64,64] fp32
// All-fp16 pipeline, batches in QUADS. gemm1 = LDS-staged 128x128 block
// (4 waves 2x2, XOR-swizzled LDS, conflict-free ds_read_b128), stores
// E' = exp(f - lmax) fp16 line-coalesced; stats per 64-row slot (64/batch).
// gemm2 = pure fp16 GEMM, P = E' * sca, partial fp16.
//   k_prep_w  : weights -> wAll fp16 [384][256], Wc fp16 [256][128]
//   k_split_x : transpose x -> xT fp16 [b][n][c]
//   k_proj    : fp16 GEMM 64x64/wave -> th/ph fp16 [b][n][c], gT fp16 [b][c][n]
//   k_gemm1   : E'[bi][n][m] = exp(theta·phi - lmax[rb][m]); lmax/lsum[64][m]
//   k_prep    : cmax/ssum from lmax/lsum; sca[bi][rb][m] fp16; gs fp16 = g*rcp
//   k_gemm2   : partial[bi][kc][n][c] (fp16) = sum_m gs[c][m]·(E'[n][m]*sca)
//   k_reduce  : yT[b][n][c] fp16 = sum_kc partial (fp32 accum)
//   k_conv    : out = Wc·yT + Wb + x   (at HBM BW ceiling)

#define IC   128
#define CIN  256
#define NPOS 4096
#define NB   8

typedef _Float16 f16;
typedef __attribute__((ext_vector_type(8))) _Float16 f16x8;
typedef __attribute__((ext_vector_type(4))) _Float16 f16x4;
typedef __attribute__((ext_vector_type(4))) float f32x4;
typedef __attribute__((ext_vector_type(4))) float fvec4;

#define MFMA16(a, b, c) __builtin_amdgcn_mfma_f32_16x16x32_f16((a), (b), (c), 0, 0, 0)

// ---------------- weight prep: wAll fp16 [384][256], Wc fp16 [256][128] ----------------
__global__ __launch_bounds__(256) void k_prep_w(
    const float* __restrict__ gw, const float* __restrict__ tw, const float* __restrict__ pw,
    const float* __restrict__ Ww, f16* __restrict__ wAll, f16* __restrict__ Wc)
{
    const int idx = (blockIdx.x * 256 + threadIdx.x) * 4;
    if (idx < 384 * 256) {
        const int row = idx >> 8, col = idx & 255;
        const float* src = (row < 128) ? (gw + row * 256)
                         : (row < 256) ? (tw + (row - 128) * 256)
                                       : (pw + (row - 256) * 256);
        fvec4 v = *reinterpret_cast<const fvec4*>(src + col);
        f16x4 o = { (f16)v[0], (f16)v[1], (f16)v[2], (f16)v[3] };
        *reinterpret_cast<f16x4*>(wAll + idx) = o;
    } else {
        const int j = idx - 384 * 256;          // over 256*128
        fvec4 v = *reinterpret_cast<const fvec4*>(Ww + j);
        f16x4 o = { (f16)v[0], (f16)v[1], (f16)v[2], (f16)v[3] };
        *reinterpret_cast<f16x4*>(Wc + j) = o;
    }
}

// ---------------- transpose x: [b][c][n] fp32 -> [b][n][c] fp16 ----------------
__global__ __launch_bounds__(256) void k_split_x(
    const float* __restrict__ x, f16* __restrict__ xT)
{
    __shared__ float tile[64][65];
    const int b  = blockIdx.z;
    const int c0 = blockIdx.y * 64;
    const int n0 = blockIdx.x * 64;
    const int t  = threadIdx.x;
    {
        const int cc = t >> 4, nn = (t & 15) * 4;
        const float* src = x + ((size_t)b * CIN + c0) * NPOS + n0;
#pragma unroll
        for (int p = 0; p < 4; ++p) {
            fvec4 v = *reinterpret_cast<const fvec4*>(src + (size_t)(cc + p * 16) * NPOS + nn);
            tile[cc + p * 16][nn + 0] = v[0];
            tile[cc + p * 16][nn + 1] = v[1];
            tile[cc + p * 16][nn + 2] = v[2];
            tile[cc + p * 16][nn + 3] = v[3];
        }
    }
    __syncthreads();
    {
        const int c4 = (t & 15) * 4, nr = t >> 4;
#pragma unroll
        for (int p = 0; p < 4; ++p) {
            const int n = nr + p * 16;
            f16x4 o = { (f16)tile[c4 + 0][n], (f16)tile[c4 + 1][n],
                        (f16)tile[c4 + 2][n], (f16)tile[c4 + 3][n] };
            *reinterpret_cast<f16x4*>(xT + ((size_t)b * NPOS + n0 + n) * CIN + c0 + c4) = o;
        }
    }
}

// ---------------- projections: fp16 GEMM, 64x64 per wave ----------------
__global__ __launch_bounds__(256) void k_proj(
    const f16* __restrict__ xT, const f16* __restrict__ wAll,
    const float* __restrict__ gb, const float* __restrict__ tb, const float* __restrict__ pb,
    f16* __restrict__ th, f16* __restrict__ ph, f16* __restrict__ gT)
{
    const int w    = threadIdx.x >> 6;
    const int lane = threadIdx.x & 63;
    const int lrow = lane & 15;
    const int kg   = lane >> 4;
    const int b    = blockIdx.z;
    const int c0   = blockIdx.y * 64;              // [0,384)
    const int n0   = blockIdx.x * 256 + w * 64;

    const f16* X = xT + (size_t)b * NPOS * CIN;

    f32x4 acc[4][4] = {};
#pragma unroll
    for (int ks = 0; ks < 8; ++ks) {
        const int k = ks * 32 + kg * 8;
        f16x8 a[4], bv[4];
#pragma unroll
        for (int i = 0; i < 4; ++i) {
            a[i]  = *reinterpret_cast<const f16x8*>(wAll + (size_t)(c0 + i * 16 + lrow) * CIN + k);
            bv[i] = *reinterpret_cast<const f16x8*>(X + (size_t)(n0 + i * 16 + lrow) * CIN + k);
        }
#pragma unroll
        for (int i = 0; i < 4; ++i)
#pragma unroll
            for (int j = 0; j < 4; ++j)
                acc[i][j] = MFMA16(a[i], bv[j], acc[i][j]);
    }
    const int set = c0 >> 7;                 // 0:g 1:theta 2:phi
    if (set == 0) {
#pragma unroll
        for (int i = 0; i < 4; ++i) {
            const int c = c0 + i * 16 + kg * 4;
#pragma unroll
            for (int j = 0; j < 4; ++j) {
                const int n = n0 + j * 16 + lrow;
#pragma unroll
                for (int r = 0; r < 4; ++r)
                    gT[((size_t)b * IC + c + r) * NPOS + n] = (f16)(acc[i][j][r] + gb[c + r]);
            }
        }
    } else {
        const float* Bi = (set == 1) ? tb : pb;
        f16* dst = (set == 1) ? th : ph;
        const int cl0 = (c0 & 127);
#pragma unroll
        for (int i = 0; i < 4; ++i) {
            const int c = cl0 + i * 16 + kg * 4;
#pragma unroll
            for (int j = 0; j < 4; ++j) {
                const int n = n0 + j * 16 + lrow;
                f16x4 o = { (f16)(acc[i][j][0] + Bi[c + 0]), (f16)(acc[i][j][1] + Bi[c + 1]),
                            (f16)(acc[i][j][2] + Bi[c + 2]), (f16)(acc[i][j][3] + Bi[c + 3]) };
                *reinterpret_cast<f16x4*>(dst + ((size_t)b * NPOS + n) * IC + c) = o;
            }
        }
    }
}

// ---- GEMM1 (quad): LDS-staged 128x128 block, 4 waves (2x2), f^T orientation.
//      A = phi tile (rows m), B = theta tile (rows n), both XOR-swizzled in
//      16B chunks (chunk ^= row&7) -> conflict-free ds_read_b128, 16B-aligned.
//      Wave (wm,wn) computes m = mblk*128+wm*64+..., n = nblk*128+wn*64+...
//      Stores Ep[n][m] = fp16(exp(f - lmax)) line-coalesced; lmax/lsum[64][m]. ----
__global__ __launch_bounds__(256, 2) void k_gemm1(
    const f16* __restrict__ th, const f16* __restrict__ ph,
    f16* __restrict__ Ep, float* __restrict__ lmax, float* __restrict__ lsum, int b0)
{
    __shared__ f16 Alds[128 * 128];   // phi tile (m rows)
    __shared__ f16 Blds[128 * 128];   // theta tile (n rows)
    const int t    = threadIdx.x;
    const int w    = t >> 6;
    const int lane = t & 63;
    const int lrow = lane & 15;
    const int kg   = lane >> 4;
    const int wm   = w & 1;
    const int wn   = w >> 1;
    const int bi   = blockIdx.x >> 10;        // 0..3
    const int rest = blockIdx.x & 1023;
    const int mblk = rest & 31;
    const int nblk = rest >> 5;

    const f16* Ag = ph + (size_t)(b0 + bi) * NPOS * IC + (size_t)(mblk * 128) * IC;
    const f16* Bg = th + (size_t)(b0 + bi) * NPOS * IC + (size_t)(nblk * 128) * IC;

    // stage both tiles: thread t loads rows (t>>4)+16*it, 16B chunk (t&15)
    {
        const int trow = t >> 4;
        const int tc   = t & 15;
#pragma unroll
        for (int it = 0; it < 8; ++it) {
            const int row = trow + it * 16;
            const int cs  = tc ^ (row & 7);
            *reinterpret_cast<f16x8*>(&Alds[row * 128 + cs * 8]) =
                *reinterpret_cast<const f16x8*>(Ag + (size_t)row * IC + tc * 8);
            *reinterpret_cast<f16x8*>(&Blds[row * 128 + cs * 8]) =
                *reinterpret_cast<const f16x8*>(Bg + (size_t)row * IC + tc * 8);
        }
    }
    __syncthreads();

    f32x4 acc[4][4] = {};
#pragma unroll
    for (int ks = 0; ks < 4; ++ks) {
        f16x8 a[4], bv[4];
#pragma unroll
        for (int i = 0; i < 4; ++i) {
            const int mr = wm * 64 + i * 16 + lrow;
            const int cs = (ks * 4 + kg) ^ (mr & 7);
            a[i] = *reinterpret_cast<const f16x8*>(&Alds[mr * 128 + cs * 8]);
        }
#pragma unroll
        for (int j = 0; j < 4; ++j) {
            const int nr = wn * 64 + j * 16 + lrow;
            const int cs = (ks * 4 + kg) ^ (nr & 7);
            bv[j] = *reinterpret_cast<const f16x8*>(&Blds[nr * 128 + cs * 8]);
        }
#pragma unroll
        for (int i = 0; i < 4; ++i)
#pragma unroll
            for (int j = 0; j < 4; ++j)
                acc[i][j] = MFMA16(a[i], bv[j], acc[i][j]);
    }

    const int m0 = mblk * 128 + wm * 64;
    const int n0 = nblk * 128 + wn * 64;
    f16* eb = Ep + (size_t)bi * NPOS * NPOS;

    // pass A: per-m column max over this wave's 64 n (in-reg j + shfl lrow)
    f32x4 cm[4];
#pragma unroll
    for (int i = 0; i < 4; ++i)
#pragma unroll
        for (int r = 0; r < 4; ++r) {
            float c = fmaxf(fmaxf(acc[i][0][r], acc[i][1][r]),
                            fmaxf(acc[i][2][r], acc[i][3][r]));
            c = fmaxf(c, __shfl_xor(c, 1));
            c = fmaxf(c, __shfl_xor(c, 2));
            c = fmaxf(c, __shfl_xor(c, 4));
            c = fmaxf(c, __shfl_xor(c, 8));
            cm[i][r] = c;
        }

    // pass B: j-outer / i-inner — line-coalesced stores + running sums
    f32x4 s[4] = {};
#pragma unroll
    for (int j = 0; j < 4; ++j) {
        f16* rowp = eb + (size_t)(n0 + j * 16 + lrow) * NPOS + m0 + kg * 4;
#pragma unroll
        for (int i = 0; i < 4; ++i) {
            f16x4 ev;
#pragma unroll
            for (int r = 0; r < 4; ++r) {
                float e = __expf(acc[i][j][r] - cm[i][r]);
                s[i][r] += e;
                ev[r] = (f16)e;
            }
            *reinterpret_cast<f16x4*>(rowp + i * 16) = ev;
        }
    }

    // stats out (64-row slots)
    const int rowblk = nblk * 2 + wn;         // 0..63
#pragma unroll
    for (int i = 0; i < 4; ++i)
#pragma unroll
        for (int r = 0; r < 4; ++r) {
            float ss = s[i][r];
            ss += __shfl_xor(ss, 1);
            ss += __shfl_xor(ss, 2);
            ss += __shfl_xor(ss, 4);
            ss += __shfl_xor(ss, 8);
            if (lrow == 0) {
                const size_t off = ((size_t)bi * 64 + rowblk) * NPOS + m0 + i * 16 + kg * 4 + r;
                lmax[off] = cm[i][r];
                lsum[off] = ss;
            }
        }
}

// ---- prep (quad): cmax/ssum over 64 slots; sca fp16; gs = g/ssum ----
__global__ __launch_bounds__(256) void k_prep(
    const float* __restrict__ lmax, const float* __restrict__ lsum,
    const f16* __restrict__ gT, f16* __restrict__ sca, f16* __restrict__ gs, int b0)
{
    const int bi = blockIdx.y;
    const int m  = blockIdx.x * 256 + threadIdx.x;
    const float* lm = lmax + (size_t)bi * 64 * NPOS;
    const float* ls = lsum + (size_t)bi * 64 * NPOS;
    float cm = -3.0e38f;
#pragma unroll 8
    for (int rb = 0; rb < 64; ++rb)
        cm = fmaxf(cm, lm[(size_t)rb * NPOS + m]);
    float s = 0.f;
    f16* scab = sca + (size_t)bi * 64 * NPOS;
#pragma unroll 8
    for (int rb = 0; rb < 64; ++rb) {
        float e = __expf(lm[(size_t)rb * NPOS + m] - cm);
        s += e * ls[(size_t)rb * NPOS + m];
        scab[(size_t)rb * NPOS + m] = (f16)e;
    }
    const float rc = 1.0f / s;
    const f16* gb = gT + (size_t)(b0 + bi) * IC * NPOS;
    f16* gsb = gs + (size_t)bi * IC * NPOS;
#pragma unroll 8
    for (int c = 0; c < IC; ++c)
        gsb[(size_t)c * NPOS + m] = (f16)((float)gb[(size_t)c * NPOS + m] * rc);
}

// ---- GEMM2 (quad): 32n x 128c per wave; P = E'*sca; kc=4; partial fp16 ----
__global__ __launch_bounds__(256) void k_gemm2(
    const f16* __restrict__ Ep, const f16* __restrict__ sca,
    const f16* __restrict__ gs, f16* __restrict__ partial)
{
    const int w    = threadIdx.x >> 6;
    const int lane = threadIdx.x & 63;
    const int lrow = lane & 15;
    const int kg   = lane >> 4;
    const int gwid = blockIdx.x * 4 + w;      // 0..2047
    const int bi   = gwid >> 9;               // 0..3
    const int rest = gwid & 511;
    const int kc   = rest & 3;                // m-chunk of 1024
    const int nb   = rest >> 2;               // 0..127, n-block of 32
    const int n0   = nb * 32;
    const int rb   = n0 >> 6;                 // 64-row stats slot

    const f16* e0row = Ep + (size_t)bi * NPOS * NPOS + (size_t)(n0 + lrow) * NPOS;
    const f16* e1row = e0row + (size_t)16 * NPOS;
    const f16* srow  = sca + ((size_t)bi * 64 + rb) * NPOS;
    const f16* gsb   = gs + (size_t)bi * IC * NPOS;

    f32x4 acc[8][2] = {};
#pragma unroll 2
    for (int ks = 0; ks < 32; ++ks) {
        const int k = kc * 1024 + ks * 32 + kg * 8;
        f16x8 sv = *reinterpret_cast<const f16x8*>(srow + k);
        f16x8 eA = *reinterpret_cast<const f16x8*>(e0row + k) * sv;
        f16x8 eB = *reinterpret_cast<const f16x8*>(e1row + k) * sv;
#pragma unroll
        for (int i = 0; i < 8; ++i) {
            f16x8 a = *reinterpret_cast<const f16x8*>(gsb + (size_t)(i * 16 + lrow) * NPOS + k);
            acc[i][0] = MFMA16(a, eA, acc[i][0]);
            acc[i][1] = MFMA16(a, eB, acc[i][1]);
        }
    }
    f16* pb = partial + ((size_t)bi * 4 + kc) * NPOS * IC;
#pragma unroll
    for (int i = 0; i < 8; ++i)
#pragma unroll
        for (int j = 0; j < 2; ++j) {
            f16x4 o = { (f16)acc[i][j][0], (f16)acc[i][j][1],
                        (f16)acc[i][j][2], (f16)acc[i][j][3] };
            *reinterpret_cast<f16x4*>(pb + (size_t)(n0 + j * 16 + lrow) * IC
                                         + i * 16 + kg * 4) = o;
        }
}

// ---------------- reduce partials (quad, fp16 in / fp32 accum) -> yT fp16 ----------------
__global__ __launch_bounds__(256) void k_reduce(
    const f16* __restrict__ partial, f16* __restrict__ yT, int b0)
{
    const int bi  = blockIdx.y;
    const int idx = blockIdx.x * 256 + threadIdx.x;   // over NPOS*IC/8
    const f16x8* p = reinterpret_cast<const f16x8*>(partial + (size_t)bi * 4 * NPOS * IC);
    float s[8] = {};
#pragma unroll
    for (int kc = 0; kc < 4; ++kc) {
        f16x8 v = p[(size_t)kc * (NPOS * IC / 8) + idx];
#pragma unroll
        for (int k = 0; k < 8; ++k)
            s[k] += (float)v[k];
    }
    f16x8 o;
#pragma unroll
    for (int k = 0; k < 8; ++k)
        o[k] = (f16)s[k];
    *reinterpret_cast<f16x8*>(yT + (size_t)(b0 + bi) * NPOS * IC + (size_t)idx * 8) = o;
}

// ---------------- final conv + residual: 64x64 per wave ----------------
__global__ __launch_bounds__(256) void k_conv(
    const float* __restrict__ x, const f16* __restrict__ Wc, const float* __restrict__ Wb,
    const f16* __restrict__ yT, float* __restrict__ out)
{
    const int w    = threadIdx.x >> 6;
    const int lane = threadIdx.x & 63;
    const int lrow = lane & 15;
    const int kg   = lane >> 4;
    const int gwid = blockIdx.x * 4 + w;      // 0..2047
    const int ob   = gwid & 3;                // o-block of 64
    const int nb   = (gwid >> 2) & 63;        // n-block of 64
    const int b    = gwid >> 8;
    const int o0   = ob * 64;
    const int n0   = nb * 64;

    const f16* Y = yT + (size_t)b * NPOS * IC;
    f32x4 acc[4][4] = {};
#pragma unroll
    for (int ks = 0; ks < 4; ++ks) {
        const int k = ks * 32 + kg * 8;
        f16x8 a[4], bv[4];
#pragma unroll
        for (int i = 0; i < 4; ++i) {
            a[i]  = *reinterpret_cast<const f16x8*>(Wc + (size_t)(o0 + i * 16 + lrow) * IC + k);
            bv[i] = *reinterpret_cast<const f16x8*>(Y + (size_t)(n0 + i * 16 + lrow) * IC + k);
        }
#pragma unroll
        for (int i = 0; i < 4; ++i)
#pragma unroll
            for (int j = 0; j < 4; ++j)
                acc[i][j] = MFMA16(a[i], bv[j], acc[i][j]);
    }
#pragma unroll
    for (int i = 0; i < 4; ++i) {
        const int o = o0 + i * 16 + kg * 4;
#pragma unroll
        for (int j = 0; j < 4; ++j) {
            const int n = n0 + j * 16 + lrow;
#pragma unroll
            for (int r = 0; r < 4; ++r) {
                const size_t off = ((size_t)b * CIN + o + r) * NPOS + n;
                out[off] = acc[i][j][r] + x[off] + Wb[o + r];
            }
        }
    }
}

extern "C" void kernel_launch(void* const* d_in, const int* in_sizes, int n_in,
                              void* d_out, int out_size, void* d_ws, size_t ws_size,
                              hipStream_t stream)
{
    const float* x  = (const float*)d_in[0];
    const float* gw = (const float*)d_in[1];
    const float* gb = (const float*)d_in[2];
    const float* tw = (const float*)d_in[3];
    const float* tb = (const float*)d_in[4];
    const float* pw = (const float*)d_in[5];
    const float* pb = (const float*)d_in[6];
    const float* Ww = (const float*)d_in[7];
    const float* Wb = (const float*)d_in[8];
    float* out = (float*)d_out;

    char* ws = (char*)d_ws;
    size_t off = 0;
    auto alloc = [&](size_t bytes) -> char* {
        char* p = ws + off;
        off += (bytes + 255) & ~(size_t)255;
        return p;
    };
    f16* xT   = (f16*)alloc((size_t)NB * NPOS * CIN * 2);        // 16.8 MB
    f16* wAll = (f16*)alloc((size_t)384 * 256 * 2);
    f16* Wc   = (f16*)alloc((size_t)CIN * IC * 2);
    f16* th   = (f16*)alloc((size_t)NB * NPOS * IC * 2);         // 8.4 MB
    f16* ph   = (f16*)alloc((size_t)NB * NPOS * IC * 2);
    f16* gT   = (f16*)alloc((size_t)NB * NPOS * IC * 2);
    f16* Ep   = (f16*)alloc((size_t)4 * NPOS * NPOS * 2);        // 134 MB (quad)
    float* lmax = (float*)alloc((size_t)4 * 64 * NPOS * 4);      // 4.2 MB
    float* lsum = (float*)alloc((size_t)4 * 64 * NPOS * 4);
    f16* sca  = (f16*)alloc((size_t)4 * 64 * NPOS * 2);          // 2.1 MB
    f16* gs   = (f16*)alloc((size_t)4 * IC * NPOS * 2);          // 4.2 MB
    f16* partial = (f16*)alloc((size_t)4 * 4 * NPOS * IC * 2);   // 16.8 MB (quad)
    f16* yT   = (f16*)alloc((size_t)NB * NPOS * IC * 2);         // 8.4 MB

    k_prep_w<<<128, 256, 0, stream>>>(gw, tw, pw, Ww, wAll, Wc);
    k_split_x<<<dim3(64, 4, 8), 256, 0, stream>>>(x, xT);
    k_proj<<<dim3(16, 6, 8), 256, 0, stream>>>(xT, wAll, gb, tb, pb, th, ph, gT);

    for (int b0 = 0; b0 < NB; b0 += 4) {
        k_gemm1<<<4096, 256, 0, stream>>>(th, ph, Ep, lmax, lsum, b0);
        k_prep<<<dim3(16, 4), 256, 0, stream>>>(lmax, lsum, gT, sca, gs, b0);
        k_gemm2<<<512, 256, 0, stream>>>(Ep, sca, gs, partial);
        k_reduce<<<dim3(256, 4), 256, 0, stream>>>(partial, yT, b0);
    }
    k_conv<<<dim3(512), 256, 0, stream>>>(x, Wc, Wb, yT, out);
}

// Round 14
// 356.560 us; speedup vs baseline: 1.3153x; 1.2783x over previous
//
#include <hip/hip_runtime.h>
#include <hip/hip_bf16.h>

// NonLocalBlock2D: x[8,256,64,64] fp32
// All-fp16 pipeline, batches in QUADS. gemm1 AND gemm2 are LDS-staged
// 128x128-block GEMMs (4 waves 2x2, XOR-swizzled LDS, conflict-free
// ds_read_b128, coalesced full-line staging).
//   k_prep_w  : weights -> wAll fp16 [384][256], Wc fp16 [256][128]
//   k_split_x : transpose x -> xT fp16 [b][n][c]
//   k_proj    : fp16 GEMM 64x64/wave -> th/ph fp16 [b][n][c], gT fp16 [b][c][n]
//   k_gemm1   : E'[bi][n][m] = exp(theta·phi - lmax[rb][m]); lmax/lsum[64][m]
//   k_prep    : cmax/ssum from lmax/lsum; sca[bi][rb][m] fp16; gs fp16 = g*rcp
//   k_gemm2   : LDS-staged: partial[bi][kc][n][c] (fp16) = sum_m gs·(E'*sca)
//   k_reduce  : yT[b][n][c] fp16 = sum_kc partial (fp32 accum)
//   k_conv    : out = Wc·yT + Wb + x   (at HBM BW ceiling)

#define IC   128
#define CIN  256
#define NPOS 4096
#define NB   8

typedef _Float16 f16;
typedef __attribute__((ext_vector_type(8))) _Float16 f16x8;
typedef __attribute__((ext_vector_type(4))) _Float16 f16x4;
typedef __attribute__((ext_vector_type(4))) float f32x4;
typedef __attribute__((ext_vector_type(4))) float fvec4;

#define MFMA16(a, b, c) __builtin_amdgcn_mfma_f32_16x16x32_f16((a), (b), (c), 0, 0, 0)

// ---------------- weight prep: wAll fp16 [384][256], Wc fp16 [256][128] ----------------
__global__ __launch_bounds__(256) void k_prep_w(
    const float* __restrict__ gw, const float* __restrict__ tw, const float* __restrict__ pw,
    const float* __restrict__ Ww, f16* __restrict__ wAll, f16* __restrict__ Wc)
{
    const int idx = (blockIdx.x * 256 + threadIdx.x) * 4;
    if (idx < 384 * 256) {
        const int row = idx >> 8, col = idx & 255;
        const float* src = (row < 128) ? (gw + row * 256)
                         : (row < 256) ? (tw + (row - 128) * 256)
                                       : (pw + (row - 256) * 256);
        fvec4 v = *reinterpret_cast<const fvec4*>(src + col);
        f16x4 o = { (f16)v[0], (f16)v[1], (f16)v[2], (f16)v[3] };
        *reinterpret_cast<f16x4*>(wAll + idx) = o;
    } else {
        const int j = idx - 384 * 256;          // over 256*128
        fvec4 v = *reinterpret_cast<const fvec4*>(Ww + j);
        f16x4 o = { (f16)v[0], (f16)v[1], (f16)v[2], (f16)v[3] };
        *reinterpret_cast<f16x4*>(Wc + j) = o;
    }
}

// ---------------- transpose x: [b][c][n] fp32 -> [b][n][c] fp16 ----------------
__global__ __launch_bounds__(256) void k_split_x(
    const float* __restrict__ x, f16* __restrict__ xT)
{
    __shared__ float tile[64][65];
    const int b  = blockIdx.z;
    const int c0 = blockIdx.y * 64;
    const int n0 = blockIdx.x * 64;
    const int t  = threadIdx.x;
    {
        const int cc = t >> 4, nn = (t & 15) * 4;
        const float* src = x + ((size_t)b * CIN + c0) * NPOS + n0;
#pragma unroll
        for (int p = 0; p < 4; ++p) {
            fvec4 v = *reinterpret_cast<const fvec4*>(src + (size_t)(cc + p * 16) * NPOS + nn);
            tile[cc + p * 16][nn + 0] = v[0];
            tile[cc + p * 16][nn + 1] = v[1];
            tile[cc + p * 16][nn + 2] = v[2];
            tile[cc + p * 16][nn + 3] = v[3];
        }
    }
    __syncthreads();
    {
        const int c4 = (t & 15) * 4, nr = t >> 4;
#pragma unroll
        for (int p = 0; p < 4; ++p) {
            const int n = nr + p * 16;
            f16x4 o = { (f16)tile[c4 + 0][n], (f16)tile[c4 + 1][n],
                        (f16)tile[c4 + 2][n], (f16)tile[c4 + 3][n] };
            *reinterpret_cast<f16x4*>(xT + ((size_t)b * NPOS + n0 + n) * CIN + c0 + c4) = o;
        }
    }
}

// ---------------- projections: fp16 GEMM, 64x64 per wave ----------------
__global__ __launch_bounds__(256) void k_proj(
    const f16* __restrict__ xT, const f16* __restrict__ wAll,
    const float* __restrict__ gb, const float* __restrict__ tb, const float* __restrict__ pb,
    f16* __restrict__ th, f16* __restrict__ ph, f16* __restrict__ gT)
{
    const int w    = threadIdx.x >> 6;
    const int lane = threadIdx.x & 63;
    const int lrow = lane & 15;
    const int kg   = lane >> 4;
    const int b    = blockIdx.z;
    const int c0   = blockIdx.y * 64;              // [0,384)
    const int n0   = blockIdx.x * 256 + w * 64;

    const f16* X = xT + (size_t)b * NPOS * CIN;

    f32x4 acc[4][4] = {};
#pragma unroll
    for (int ks = 0; ks < 8; ++ks) {
        const int k = ks * 32 + kg * 8;
        f16x8 a[4], bv[4];
#pragma unroll
        for (int i = 0; i < 4; ++i) {
            a[i]  = *reinterpret_cast<const f16x8*>(wAll + (size_t)(c0 + i * 16 + lrow) * CIN + k);
            bv[i] = *reinterpret_cast<const f16x8*>(X + (size_t)(n0 + i * 16 + lrow) * CIN + k);
        }
#pragma unroll
        for (int i = 0; i < 4; ++i)
#pragma unroll
            for (int j = 0; j < 4; ++j)
                acc[i][j] = MFMA16(a[i], bv[j], acc[i][j]);
    }
    const int set = c0 >> 7;                 // 0:g 1:theta 2:phi
    if (set == 0) {
#pragma unroll
        for (int i = 0; i < 4; ++i) {
            const int c = c0 + i * 16 + kg * 4;
#pragma unroll
            for (int j = 0; j < 4; ++j) {
                const int n = n0 + j * 16 + lrow;
#pragma unroll
                for (int r = 0; r < 4; ++r)
                    gT[((size_t)b * IC + c + r) * NPOS + n] = (f16)(acc[i][j][r] + gb[c + r]);
            }
        }
    } else {
        const float* Bi = (set == 1) ? tb : pb;
        f16* dst = (set == 1) ? th : ph;
        const int cl0 = (c0 & 127);
#pragma unroll
        for (int i = 0; i < 4; ++i) {
            const int c = cl0 + i * 16 + kg * 4;
#pragma unroll
            for (int j = 0; j < 4; ++j) {
                const int n = n0 + j * 16 + lrow;
                f16x4 o = { (f16)(acc[i][j][0] + Bi[c + 0]), (f16)(acc[i][j][1] + Bi[c + 1]),
                            (f16)(acc[i][j][2] + Bi[c + 2]), (f16)(acc[i][j][3] + Bi[c + 3]) };
                *reinterpret_cast<f16x4*>(dst + ((size_t)b * NPOS + n) * IC + c) = o;
            }
        }
    }
}

// ---- GEMM1 (quad): LDS-staged 128x128 block, 4 waves (2x2), f^T orientation. ----
__global__ __launch_bounds__(256, 2) void k_gemm1(
    const f16* __restrict__ th, const f16* __restrict__ ph,
    f16* __restrict__ Ep, float* __restrict__ lmax, float* __restrict__ lsum, int b0)
{
    __shared__ f16 Alds[128 * 128];   // phi tile (m rows)
    __shared__ f16 Blds[128 * 128];   // theta tile (n rows)
    const int t    = threadIdx.x;
    const int w    = t >> 6;
    const int lane = t & 63;
    const int lrow = lane & 15;
    const int kg   = lane >> 4;
    const int wm   = w & 1;
    const int wn   = w >> 1;
    const int bi   = blockIdx.x >> 10;        // 0..3
    const int rest = blockIdx.x & 1023;
    const int mblk = rest & 31;
    const int nblk = rest >> 5;

    const f16* Ag = ph + (size_t)(b0 + bi) * NPOS * IC + (size_t)(mblk * 128) * IC;
    const f16* Bg = th + (size_t)(b0 + bi) * NPOS * IC + (size_t)(nblk * 128) * IC;

    {
        const int trow = t >> 4;
        const int tc   = t & 15;
#pragma unroll
        for (int it = 0; it < 8; ++it) {
            const int row = trow + it * 16;
            const int cs  = tc ^ (row & 7);
            *reinterpret_cast<f16x8*>(&Alds[row * 128 + cs * 8]) =
                *reinterpret_cast<const f16x8*>(Ag + (size_t)row * IC + tc * 8);
            *reinterpret_cast<f16x8*>(&Blds[row * 128 + cs * 8]) =
                *reinterpret_cast<const f16x8*>(Bg + (size_t)row * IC + tc * 8);
        }
    }
    __syncthreads();

    f32x4 acc[4][4] = {};
#pragma unroll
    for (int ks = 0; ks < 4; ++ks) {
        f16x8 a[4], bv[4];
#pragma unroll
        for (int i = 0; i < 4; ++i) {
            const int mr = wm * 64 + i * 16 + lrow;
            const int cs = (ks * 4 + kg) ^ (mr & 7);
            a[i] = *reinterpret_cast<const f16x8*>(&Alds[mr * 128 + cs * 8]);
        }
#pragma unroll
        for (int j = 0; j < 4; ++j) {
            const int nr = wn * 64 + j * 16 + lrow;
            const int cs = (ks * 4 + kg) ^ (nr & 7);
            bv[j] = *reinterpret_cast<const f16x8*>(&Blds[nr * 128 + cs * 8]);
        }
#pragma unroll
        for (int i = 0; i < 4; ++i)
#pragma unroll
            for (int j = 0; j < 4; ++j)
                acc[i][j] = MFMA16(a[i], bv[j], acc[i][j]);
    }

    const int m0 = mblk * 128 + wm * 64;
    const int n0 = nblk * 128 + wn * 64;
    f16* eb = Ep + (size_t)bi * NPOS * NPOS;

    // pass A: per-m column max over this wave's 64 n
    f32x4 cm[4];
#pragma unroll
    for (int i = 0; i < 4; ++i)
#pragma unroll
        for (int r = 0; r < 4; ++r) {
            float c = fmaxf(fmaxf(acc[i][0][r], acc[i][1][r]),
                            fmaxf(acc[i][2][r], acc[i][3][r]));
            c = fmaxf(c, __shfl_xor(c, 1));
            c = fmaxf(c, __shfl_xor(c, 2));
            c = fmaxf(c, __shfl_xor(c, 4));
            c = fmaxf(c, __shfl_xor(c, 8));
            cm[i][r] = c;
        }

    // pass B: j-outer / i-inner — line-coalesced stores + running sums
    f32x4 s[4] = {};
#pragma unroll
    for (int j = 0; j < 4; ++j) {
        f16* rowp = eb + (size_t)(n0 + j * 16 + lrow) * NPOS + m0 + kg * 4;
#pragma unroll
        for (int i = 0; i < 4; ++i) {
            f16x4 ev;
#pragma unroll
            for (int r = 0; r < 4; ++r) {
                float e = __expf(acc[i][j][r] - cm[i][r]);
                s[i][r] += e;
                ev[r] = (f16)e;
            }
            *reinterpret_cast<f16x4*>(rowp + i * 16) = ev;
        }
    }

    // stats out (64-row slots)
    const int rowblk = nblk * 2 + wn;         // 0..63
#pragma unroll
    for (int i = 0; i < 4; ++i)
#pragma unroll
        for (int r = 0; r < 4; ++r) {
            float ss = s[i][r];
            ss += __shfl_xor(ss, 1);
            ss += __shfl_xor(ss, 2);
            ss += __shfl_xor(ss, 4);
            ss += __shfl_xor(ss, 8);
            if (lrow == 0) {
                const size_t off = ((size_t)bi * 64 + rowblk) * NPOS + m0 + i * 16 + kg * 4 + r;
                lmax[off] = cm[i][r];
                lsum[off] = ss;
            }
        }
}

// ---- prep (quad): cmax/ssum over 64 slots; sca fp16; gs = g/ssum ----
__global__ __launch_bounds__(256) void k_prep(
    const float* __restrict__ lmax, const float* __restrict__ lsum,
    const f16* __restrict__ gT, f16* __restrict__ sca, f16* __restrict__ gs, int b0)
{
    const int bi = blockIdx.y;
    const int m  = blockIdx.x * 256 + threadIdx.x;
    const float* lm = lmax + (size_t)bi * 64 * NPOS;
    const float* ls = lsum + (size_t)bi * 64 * NPOS;
    float cm = -3.0e38f;
#pragma unroll 8
    for (int rb = 0; rb < 64; ++rb)
        cm = fmaxf(cm, lm[(size_t)rb * NPOS + m]);
    float s = 0.f;
    f16* scab = sca + (size_t)bi * 64 * NPOS;
#pragma unroll 8
    for (int rb = 0; rb < 64; ++rb) {
        float e = __expf(lm[(size_t)rb * NPOS + m] - cm);
        s += e * ls[(size_t)rb * NPOS + m];
        scab[(size_t)rb * NPOS + m] = (f16)e;
    }
    const float rc = 1.0f / s;
    const f16* gb = gT + (size_t)(b0 + bi) * IC * NPOS;
    f16* gsb = gs + (size_t)bi * IC * NPOS;
#pragma unroll 8
    for (int c = 0; c < IC; ++c)
        gsb[(size_t)c * NPOS + m] = (f16)((float)gb[(size_t)c * NPOS + m] * rc);
}

// ---- GEMM2 (quad): LDS-staged 128c x 128n block, 4 waves (2x2), kc=4 chunks
//      of 1024 m, staged in 128-m sub-chunks (E' 32KB + gs 32KB, swizzled).
//      P = E'*sca applied on fragments (sv from L2, broadcast). partial fp16. ----
__global__ __launch_bounds__(256, 2) void k_gemm2(
    const f16* __restrict__ Ep, const f16* __restrict__ sca,
    const f16* __restrict__ gs, f16* __restrict__ partial)
{
    __shared__ f16 Elds[128 * 128];   // E' tile (n rows)
    __shared__ f16 Glds[128 * 128];   // gs tile (c rows)
    const int t    = threadIdx.x;
    const int w    = t >> 6;
    const int lane = t & 63;
    const int lrow = lane & 15;
    const int kg   = lane >> 4;
    const int wc   = w & 1;
    const int wn   = w >> 1;
    const int bi   = blockIdx.x >> 7;         // 0..3
    const int rest = blockIdx.x & 127;
    const int kc   = rest & 3;                // m-chunk of 1024
    const int nblk = rest >> 2;               // 0..31, n-block of 128

    const f16* Eg  = Ep + (size_t)bi * NPOS * NPOS + (size_t)(nblk * 128) * NPOS + kc * 1024;
    const f16* Gg  = gs + (size_t)bi * IC * NPOS + kc * 1024;
    const int  rb  = nblk * 2 + wn;           // wave's 64-row stats slot
    const f16* srow = sca + ((size_t)bi * 64 + rb) * NPOS + kc * 1024;

    f32x4 acc[4][4] = {};
    const int trow = t >> 4;
    const int tc   = t & 15;

    for (int sc = 0; sc < 8; ++sc) {          // 8 sub-chunks of 128 m
        if (sc) __syncthreads();
        // stage E'[128n][128m] and gs[128c][128m], coalesced full lines
#pragma unroll
        for (int it = 0; it < 8; ++it) {
            const int row = trow + it * 16;
            const int cs  = tc ^ (row & 7);
            *reinterpret_cast<f16x8*>(&Elds[row * 128 + cs * 8]) =
                *reinterpret_cast<const f16x8*>(Eg + (size_t)row * NPOS + sc * 128 + tc * 8);
            *reinterpret_cast<f16x8*>(&Glds[row * 128 + cs * 8]) =
                *reinterpret_cast<const f16x8*>(Gg + (size_t)row * NPOS + sc * 128 + tc * 8);
        }
        __syncthreads();

#pragma unroll
        for (int ks = 0; ks < 4; ++ks) {
            f16x8 sv = *reinterpret_cast<const f16x8*>(srow + sc * 128 + ks * 32 + kg * 8);
            f16x8 a[4], ev[4];
#pragma unroll
            for (int i = 0; i < 4; ++i) {
                const int cr = wc * 64 + i * 16 + lrow;
                const int cs = (ks * 4 + kg) ^ (cr & 7);
                a[i] = *reinterpret_cast<const f16x8*>(&Glds[cr * 128 + cs * 8]);
            }
#pragma unroll
            for (int j = 0; j < 4; ++j) {
                const int nr = wn * 64 + j * 16 + lrow;
                const int cs = (ks * 4 + kg) ^ (nr & 7);
                ev[j] = *reinterpret_cast<const f16x8*>(&Elds[nr * 128 + cs * 8]) * sv;
            }
#pragma unroll
            for (int i = 0; i < 4; ++i)
#pragma unroll
                for (int j = 0; j < 4; ++j)
                    acc[i][j] = MFMA16(a[i], ev[j], acc[i][j]);
        }
    }

    // store partial: n rows, c cols; j-outer/i-inner for contiguous 64B runs
    f16* pb = partial + ((size_t)bi * 4 + kc) * NPOS * IC;
    const int n0 = nblk * 128 + wn * 64;
    const int c0 = wc * 64;
#pragma unroll
    for (int j = 0; j < 4; ++j) {
        f16* rowp = pb + (size_t)(n0 + j * 16 + lrow) * IC + c0 + kg * 4;
#pragma unroll
        for (int i = 0; i < 4; ++i) {
            f16x4 o = { (f16)acc[i][j][0], (f16)acc[i][j][1],
                        (f16)acc[i][j][2], (f16)acc[i][j][3] };
            *reinterpret_cast<f16x4*>(rowp + i * 16) = o;
        }
    }
}

// ---------------- reduce partials (quad, fp16 in / fp32 accum) -> yT fp16 ----------------
__global__ __launch_bounds__(256) void k_reduce(
    const f16* __restrict__ partial, f16* __restrict__ yT, int b0)
{
    const int bi  = blockIdx.y;
    const int idx = blockIdx.x * 256 + threadIdx.x;   // over NPOS*IC/8
    const f16x8* p = reinterpret_cast<const f16x8*>(partial + (size_t)bi * 4 * NPOS * IC);
    float s[8] = {};
#pragma unroll
    for (int kc = 0; kc < 4; ++kc) {
        f16x8 v = p[(size_t)kc * (NPOS * IC / 8) + idx];
#pragma unroll
        for (int k = 0; k < 8; ++k)
            s[k] += (float)v[k];
    }
    f16x8 o;
#pragma unroll
    for (int k = 0; k < 8; ++k)
        o[k] = (f16)s[k];
    *reinterpret_cast<f16x8*>(yT + (size_t)(b0 + bi) * NPOS * IC + (size_t)idx * 8) = o;
}

// ---------------- final conv + residual: 64x64 per wave ----------------
__global__ __launch_bounds__(256) void k_conv(
    const float* __restrict__ x, const f16* __restrict__ Wc, const float* __restrict__ Wb,
    const f16* __restrict__ yT, float* __restrict__ out)
{
    const int w    = threadIdx.x >> 6;
    const int lane = threadIdx.x & 63;
    const int lrow = lane & 15;
    const int kg   = lane >> 4;
    const int gwid = blockIdx.x * 4 + w;      // 0..2047
    const int ob   = gwid & 3;                // o-block of 64
    const int nb   = (gwid >> 2) & 63;        // n-block of 64
    const int b    = gwid >> 8;
    const int o0   = ob * 64;
    const int n0   = nb * 64;

    const f16* Y = yT + (size_t)b * NPOS * IC;
    f32x4 acc[4][4] = {};
#pragma unroll
    for (int ks = 0; ks < 4; ++ks) {
        const int k = ks * 32 + kg * 8;
        f16x8 a[4], bv[4];
#pragma unroll
        for (int i = 0; i < 4; ++i) {
            a[i]  = *reinterpret_cast<const f16x8*>(Wc + (size_t)(o0 + i * 16 + lrow) * IC + k);
            bv[i] = *reinterpret_cast<const f16x8*>(Y + (size_t)(n0 + i * 16 + lrow) * IC + k);
        }
#pragma unroll
        for (int i = 0; i < 4; ++i)
#pragma unroll
            for (int j = 0; j < 4; ++j)
                acc[i][j] = MFMA16(a[i], bv[j], acc[i][j]);
    }
#pragma unroll
    for (int i = 0; i < 4; ++i) {
        const int o = o0 + i * 16 + kg * 4;
#pragma unroll
        for (int j = 0; j < 4; ++j) {
            const int n = n0 + j * 16 + lrow;
#pragma unroll
            for (int r = 0; r < 4; ++r) {
                const size_t off = ((size_t)b * CIN + o + r) * NPOS + n;
                out[off] = acc[i][j][r] + x[off] + Wb[o + r];
            }
        }
    }
}

extern "C" void kernel_launch(void* const* d_in, const int* in_sizes, int n_in,
                              void* d_out, int out_size, void* d_ws, size_t ws_size,
                              hipStream_t stream)
{
    const float* x  = (const float*)d_in[0];
    const float* gw = (const float*)d_in[1];
    const float* gb = (const float*)d_in[2];
    const float* tw = (const float*)d_in[3];
    const float* tb = (const float*)d_in[4];
    const float* pw = (const float*)d_in[5];
    const float* pb = (const float*)d_in[6];
    const float* Ww = (const float*)d_in[7];
    const float* Wb = (const float*)d_in[8];
    float* out = (float*)d_out;

    char* ws = (char*)d_ws;
    size_t off = 0;
    auto alloc = [&](size_t bytes) -> char* {
        char* p = ws + off;
        off += (bytes + 255) & ~(size_t)255;
        return p;
    };
    f16* xT   = (f16*)alloc((size_t)NB * NPOS * CIN * 2);        // 16.8 MB
    f16* wAll = (f16*)alloc((size_t)384 * 256 * 2);
    f16* Wc   = (f16*)alloc((size_t)CIN * IC * 2);
    f16* th   = (f16*)alloc((size_t)NB * NPOS * IC * 2);         // 8.4 MB
    f16* ph   = (f16*)alloc((size_t)NB * NPOS * IC * 2);
    f16* gT   = (f16*)alloc((size_t)NB * NPOS * IC * 2);
    f16* Ep   = (f16*)alloc((size_t)4 * NPOS * NPOS * 2);        // 134 MB (quad)
    float* lmax = (float*)alloc((size_t)4 * 64 * NPOS * 4);      // 4.2 MB
    float* lsum = (float*)alloc((size_t)4 * 64 * NPOS * 4);
    f16* sca  = (f16*)alloc((size_t)4 * 64 * NPOS * 2);          // 2.1 MB
    f16* gs   = (f16*)alloc((size_t)4 * IC * NPOS * 2);          // 4.2 MB
    f16* partial = (f16*)alloc((size_t)4 * 4 * NPOS * IC * 2);   // 16.8 MB (quad)
    f16* yT   = (f16*)alloc((size_t)NB * NPOS * IC * 2);         // 8.4 MB

    k_prep_w<<<128, 256, 0, stream>>>(gw, tw, pw, Ww, wAll, Wc);
    k_split_x<<<dim3(64, 4, 8), 256, 0, stream>>>(x, xT);
    k_proj<<<dim3(16, 6, 8), 256, 0, stream>>>(xT, wAll, gb, tb, pb, th, ph, gT);

    for (int b0 = 0; b0 < NB; b0 += 4) {
        k_gemm1<<<4096, 256, 0, stream>>>(th, ph, Ep, lmax, lsum, b0);
        k_prep<<<dim3(16, 4), 256, 0, stream>>>(lmax, lsum, gT, sca, gs, b0);
        k_gemm2<<<512, 256, 0, stream>>>(Ep, sca, gs, partial);
        k_reduce<<<dim3(256, 4), 256, 0, stream>>>(partial, yT, b0);
    }
    k_conv<<<dim3(512), 256, 0, stream>>>(x, Wc, Wb, yT, out);
}

// Round 15
// 342.957 us; speedup vs baseline: 1.3675x; 1.0397x over previous
//
#include <hip/hip_runtime.h>
#include <hip/hip_bf16.h>

// NonLocalBlock2D: x[8,256,64,64] fp32
// All-fp16 pipeline, batches in QUADS. gemm1 AND gemm2 are LDS-staged
// 128x128-block GEMMs with K-SPLIT staging (32KB LDS -> 4-5 blocks/CU),
// XOR-swizzled, conflict-free ds_read_b128, coalesced staging.
//   k_prep_w  : weights -> wAll fp16 [384][256], Wc fp16 [256][128]
//   k_split_x : transpose x -> xT fp16 [b][n][c]
//   k_proj    : fp16 GEMM 64x64/wave -> th/ph fp16 [b][n][c], gT fp16 [b][c][n]
//   k_gemm1   : E'[bi][n][m] = exp(theta·phi - lmax[rb][m]); lmax/lsum[64][m]
//   k_prep    : cmax/ssum from lmax/lsum; sca[bi][rb][m] fp16; gs fp16 = g*rcp
//   k_gemm2   : partial[bi][kc][n][c] (fp16) = sum_m gs·(E'*sca)
//   k_reduce  : yT[b][n][c] fp16 = sum_kc partial (fp32 accum)
//   k_conv    : out = Wc·yT + Wb + x   (at HBM BW ceiling)

#define IC   128
#define CIN  256
#define NPOS 4096
#define NB   8

typedef _Float16 f16;
typedef __attribute__((ext_vector_type(8))) _Float16 f16x8;
typedef __attribute__((ext_vector_type(4))) _Float16 f16x4;
typedef __attribute__((ext_vector_type(4))) float f32x4;
typedef __attribute__((ext_vector_type(4))) float fvec4;

#define MFMA16(a, b, c) __builtin_amdgcn_mfma_f32_16x16x32_f16((a), (b), (c), 0, 0, 0)

// ---------------- weight prep: wAll fp16 [384][256], Wc fp16 [256][128] ----------------
__global__ __launch_bounds__(256) void k_prep_w(
    const float* __restrict__ gw, const float* __restrict__ tw, const float* __restrict__ pw,
    const float* __restrict__ Ww, f16* __restrict__ wAll, f16* __restrict__ Wc)
{
    const int idx = (blockIdx.x * 256 + threadIdx.x) * 4;
    if (idx < 384 * 256) {
        const int row = idx >> 8, col = idx & 255;
        const float* src = (row < 128) ? (gw + row * 256)
                         : (row < 256) ? (tw + (row - 128) * 256)
                                       : (pw + (row - 256) * 256);
        fvec4 v = *reinterpret_cast<const fvec4*>(src + col);
        f16x4 o = { (f16)v[0], (f16)v[1], (f16)v[2], (f16)v[3] };
        *reinterpret_cast<f16x4*>(wAll + idx) = o;
    } else {
        const int j = idx - 384 * 256;          // over 256*128
        fvec4 v = *reinterpret_cast<const fvec4*>(Ww + j);
        f16x4 o = { (f16)v[0], (f16)v[1], (f16)v[2], (f16)v[3] };
        *reinterpret_cast<f16x4*>(Wc + j) = o;
    }
}

// ---------------- transpose x: [b][c][n] fp32 -> [b][n][c] fp16 ----------------
__global__ __launch_bounds__(256) void k_split_x(
    const float* __restrict__ x, f16* __restrict__ xT)
{
    __shared__ float tile[64][65];
    const int b  = blockIdx.z;
    const int c0 = blockIdx.y * 64;
    const int n0 = blockIdx.x * 64;
    const int t  = threadIdx.x;
    {
        const int cc = t >> 4, nn = (t & 15) * 4;
        const float* src = x + ((size_t)b * CIN + c0) * NPOS + n0;
#pragma unroll
        for (int p = 0; p < 4; ++p) {
            fvec4 v = *reinterpret_cast<const fvec4*>(src + (size_t)(cc + p * 16) * NPOS + nn);
            tile[cc + p * 16][nn + 0] = v[0];
            tile[cc + p * 16][nn + 1] = v[1];
            tile[cc + p * 16][nn + 2] = v[2];
            tile[cc + p * 16][nn + 3] = v[3];
        }
    }
    __syncthreads();
    {
        const int c4 = (t & 15) * 4, nr = t >> 4;
#pragma unroll
        for (int p = 0; p < 4; ++p) {
            const int n = nr + p * 16;
            f16x4 o = { (f16)tile[c4 + 0][n], (f16)tile[c4 + 1][n],
                        (f16)tile[c4 + 2][n], (f16)tile[c4 + 3][n] };
            *reinterpret_cast<f16x4*>(xT + ((size_t)b * NPOS + n0 + n) * CIN + c0 + c4) = o;
        }
    }
}

// ---------------- projections: fp16 GEMM, 64x64 per wave ----------------
__global__ __launch_bounds__(256) void k_proj(
    const f16* __restrict__ xT, const f16* __restrict__ wAll,
    const float* __restrict__ gb, const float* __restrict__ tb, const float* __restrict__ pb,
    f16* __restrict__ th, f16* __restrict__ ph, f16* __restrict__ gT)
{
    const int w    = threadIdx.x >> 6;
    const int lane = threadIdx.x & 63;
    const int lrow = lane & 15;
    const int kg   = lane >> 4;
    const int b    = blockIdx.z;
    const int c0   = blockIdx.y * 64;              // [0,384)
    const int n0   = blockIdx.x * 256 + w * 64;

    const f16* X = xT + (size_t)b * NPOS * CIN;

    f32x4 acc[4][4] = {};
#pragma unroll
    for (int ks = 0; ks < 8; ++ks) {
        const int k = ks * 32 + kg * 8;
        f16x8 a[4], bv[4];
#pragma unroll
        for (int i = 0; i < 4; ++i) {
            a[i]  = *reinterpret_cast<const f16x8*>(wAll + (size_t)(c0 + i * 16 + lrow) * CIN + k);
            bv[i] = *reinterpret_cast<const f16x8*>(X + (size_t)(n0 + i * 16 + lrow) * CIN + k);
        }
#pragma unroll
        for (int i = 0; i < 4; ++i)
#pragma unroll
            for (int j = 0; j < 4; ++j)
                acc[i][j] = MFMA16(a[i], bv[j], acc[i][j]);
    }
    const int set = c0 >> 7;                 // 0:g 1:theta 2:phi
    if (set == 0) {
#pragma unroll
        for (int i = 0; i < 4; ++i) {
            const int c = c0 + i * 16 + kg * 4;
#pragma unroll
            for (int j = 0; j < 4; ++j) {
                const int n = n0 + j * 16 + lrow;
#pragma unroll
                for (int r = 0; r < 4; ++r)
                    gT[((size_t)b * IC + c + r) * NPOS + n] = (f16)(acc[i][j][r] + gb[c + r]);
            }
        }
    } else {
        const float* Bi = (set == 1) ? tb : pb;
        f16* dst = (set == 1) ? th : ph;
        const int cl0 = (c0 & 127);
#pragma unroll
        for (int i = 0; i < 4; ++i) {
            const int c = cl0 + i * 16 + kg * 4;
#pragma unroll
            for (int j = 0; j < 4; ++j) {
                const int n = n0 + j * 16 + lrow;
                f16x4 o = { (f16)(acc[i][j][0] + Bi[c + 0]), (f16)(acc[i][j][1] + Bi[c + 1]),
                            (f16)(acc[i][j][2] + Bi[c + 2]), (f16)(acc[i][j][3] + Bi[c + 3]) };
                *reinterpret_cast<f16x4*>(dst + ((size_t)b * NPOS + n) * IC + c) = o;
            }
        }
    }
}

// ---- GEMM1 (quad): LDS-staged 128x128 block, K-split halves (32KB LDS),
//      4 waves (2x2), f^T orientation (A=phi rows m, B=theta rows n). ----
__global__ __launch_bounds__(256, 4) void k_gemm1(
    const f16* __restrict__ th, const f16* __restrict__ ph,
    f16* __restrict__ Ep, float* __restrict__ lmax, float* __restrict__ lsum, int b0)
{
    __shared__ f16 Alds[128 * 64];    // phi tile, one K-half
    __shared__ f16 Blds[128 * 64];    // theta tile, one K-half
    const int t    = threadIdx.x;
    const int w    = t >> 6;
    const int lane = t & 63;
    const int lrow = lane & 15;
    const int kg   = lane >> 4;
    const int wm   = w & 1;
    const int wn   = w >> 1;
    const int bi   = blockIdx.x >> 10;        // 0..3
    const int rest = blockIdx.x & 1023;
    const int mblk = rest & 31;
    const int nblk = rest >> 5;

    const f16* Ag = ph + (size_t)(b0 + bi) * NPOS * IC + (size_t)(mblk * 128) * IC;
    const f16* Bg = th + (size_t)(b0 + bi) * NPOS * IC + (size_t)(nblk * 128) * IC;

    const int trow = t >> 3;                  // 0..31
    const int tc   = t & 7;                   // 16B chunk 0..7

    f32x4 acc[4][4] = {};
#pragma unroll
    for (int h = 0; h < 2; ++h) {             // K halves of 64
        if (h) __syncthreads();
#pragma unroll
        for (int it = 0; it < 4; ++it) {
            const int row = trow + it * 32;
            const int cs  = tc ^ (row & 7);
            *reinterpret_cast<f16x8*>(&Alds[row * 64 + cs * 8]) =
                *reinterpret_cast<const f16x8*>(Ag + (size_t)row * IC + h * 64 + tc * 8);
            *reinterpret_cast<f16x8*>(&Blds[row * 64 + cs * 8]) =
                *reinterpret_cast<const f16x8*>(Bg + (size_t)row * IC + h * 64 + tc * 8);
        }
        __syncthreads();
#pragma unroll
        for (int ks = 0; ks < 2; ++ks) {
            f16x8 a[4], bv[4];
#pragma unroll
            for (int i = 0; i < 4; ++i) {
                const int mr = wm * 64 + i * 16 + lrow;
                const int cs = (ks * 4 + kg) ^ (mr & 7);
                a[i] = *reinterpret_cast<const f16x8*>(&Alds[mr * 64 + cs * 8]);
            }
#pragma unroll
            for (int j = 0; j < 4; ++j) {
                const int nr = wn * 64 + j * 16 + lrow;
                const int cs = (ks * 4 + kg) ^ (nr & 7);
                bv[j] = *reinterpret_cast<const f16x8*>(&Blds[nr * 64 + cs * 8]);
            }
#pragma unroll
            for (int i = 0; i < 4; ++i)
#pragma unroll
                for (int j = 0; j < 4; ++j)
                    acc[i][j] = MFMA16(a[i], bv[j], acc[i][j]);
        }
    }

    const int m0 = mblk * 128 + wm * 64;
    const int n0 = nblk * 128 + wn * 64;
    f16* eb = Ep + (size_t)bi * NPOS * NPOS;
    const float L2E = 1.4426950408889634f;

    // pass A: per-m column max over this wave's 64 n
    f32x4 cm[4], ncml[4];
#pragma unroll
    for (int i = 0; i < 4; ++i)
#pragma unroll
        for (int r = 0; r < 4; ++r) {
            float c = fmaxf(fmaxf(acc[i][0][r], acc[i][1][r]),
                            fmaxf(acc[i][2][r], acc[i][3][r]));
            c = fmaxf(c, __shfl_xor(c, 1));
            c = fmaxf(c, __shfl_xor(c, 2));
            c = fmaxf(c, __shfl_xor(c, 4));
            c = fmaxf(c, __shfl_xor(c, 8));
            cm[i][r] = c;
            ncml[i][r] = -c * L2E;
        }

    // pass B: j-outer / i-inner — line-coalesced stores + running sums
    f32x4 s[4] = {};
#pragma unroll
    for (int j = 0; j < 4; ++j) {
        f16* rowp = eb + (size_t)(n0 + j * 16 + lrow) * NPOS + m0 + kg * 4;
#pragma unroll
        for (int i = 0; i < 4; ++i) {
            f16x4 ev;
#pragma unroll
            for (int r = 0; r < 4; ++r) {
                float e = exp2f(__builtin_fmaf(acc[i][j][r], L2E, ncml[i][r]));
                s[i][r] += e;
                ev[r] = (f16)e;
            }
            *reinterpret_cast<f16x4*>(rowp + i * 16) = ev;
        }
    }

    // stats out (64-row slots)
    const int rowblk = nblk * 2 + wn;         // 0..63
#pragma unroll
    for (int i = 0; i < 4; ++i)
#pragma unroll
        for (int r = 0; r < 4; ++r) {
            float ss = s[i][r];
            ss += __shfl_xor(ss, 1);
            ss += __shfl_xor(ss, 2);
            ss += __shfl_xor(ss, 4);
            ss += __shfl_xor(ss, 8);
            if (lrow == 0) {
                const size_t off = ((size_t)bi * 64 + rowblk) * NPOS + m0 + i * 16 + kg * 4 + r;
                lmax[off] = cm[i][r];
                lsum[off] = ss;
            }
        }
}

// ---- prep (quad): cmax/ssum over 64 slots; sca fp16; gs = g/ssum ----
__global__ __launch_bounds__(256) void k_prep(
    const float* __restrict__ lmax, const float* __restrict__ lsum,
    const f16* __restrict__ gT, f16* __restrict__ sca, f16* __restrict__ gs, int b0)
{
    const int bi = blockIdx.y;
    const int m  = blockIdx.x * 256 + threadIdx.x;
    const float* lm = lmax + (size_t)bi * 64 * NPOS;
    const float* ls = lsum + (size_t)bi * 64 * NPOS;
    float cm = -3.0e38f;
#pragma unroll 8
    for (int rb = 0; rb < 64; ++rb)
        cm = fmaxf(cm, lm[(size_t)rb * NPOS + m]);
    float s = 0.f;
    f16* scab = sca + (size_t)bi * 64 * NPOS;
#pragma unroll 8
    for (int rb = 0; rb < 64; ++rb) {
        float e = __expf(lm[(size_t)rb * NPOS + m] - cm);
        s += e * ls[(size_t)rb * NPOS + m];
        scab[(size_t)rb * NPOS + m] = (f16)e;
    }
    const float rc = 1.0f / s;
    const f16* gb = gT + (size_t)(b0 + bi) * IC * NPOS;
    f16* gsb = gs + (size_t)bi * IC * NPOS;
#pragma unroll 8
    for (int c = 0; c < IC; ++c)
        gsb[(size_t)c * NPOS + m] = (f16)((float)gb[(size_t)c * NPOS + m] * rc);
}

// ---- GEMM2 (quad): LDS-staged 128c x 128n block, 64-m sub-chunks (32KB LDS),
//      4 waves (2x2), kc=4 chunks of 1024 m. P = E'*sca on fragments. ----
__global__ __launch_bounds__(256, 4) void k_gemm2(
    const f16* __restrict__ Ep, const f16* __restrict__ sca,
    const f16* __restrict__ gs, f16* __restrict__ partial)
{
    __shared__ f16 Elds[128 * 64];    // E' tile (n rows), one 64-m sub-chunk
    __shared__ f16 Glds[128 * 64];    // gs tile (c rows)
    const int t    = threadIdx.x;
    const int w    = t >> 6;
    const int lane = t & 63;
    const int lrow = lane & 15;
    const int kg   = lane >> 4;
    const int wc   = w & 1;
    const int wn   = w >> 1;
    const int bi   = blockIdx.x >> 7;         // 0..3
    const int rest = blockIdx.x & 127;
    const int kc   = rest & 3;                // m-chunk of 1024
    const int nblk = rest >> 2;               // 0..31, n-block of 128

    const f16* Eg  = Ep + (size_t)bi * NPOS * NPOS + (size_t)(nblk * 128) * NPOS + kc * 1024;
    const f16* Gg  = gs + (size_t)bi * IC * NPOS + kc * 1024;
    const int  rb  = nblk * 2 + wn;           // wave's 64-row stats slot
    const f16* srow = sca + ((size_t)bi * 64 + rb) * NPOS + kc * 1024;

    const int trow = t >> 3;                  // 0..31
    const int tc   = t & 7;                   // 16B chunk 0..7

    f32x4 acc[4][4] = {};
    for (int sc = 0; sc < 16; ++sc) {         // 16 sub-chunks of 64 m
        if (sc) __syncthreads();
#pragma unroll
        for (int it = 0; it < 4; ++it) {
            const int row = trow + it * 32;
            const int cs  = tc ^ (row & 7);
            *reinterpret_cast<f16x8*>(&Elds[row * 64 + cs * 8]) =
                *reinterpret_cast<const f16x8*>(Eg + (size_t)row * NPOS + sc * 64 + tc * 8);
            *reinterpret_cast<f16x8*>(&Glds[row * 64 + cs * 8]) =
                *reinterpret_cast<const f16x8*>(Gg + (size_t)row * NPOS + sc * 64 + tc * 8);
        }
        __syncthreads();

#pragma unroll
        for (int ks = 0; ks < 2; ++ks) {
            f16x8 sv = *reinterpret_cast<const f16x8*>(srow + sc * 64 + ks * 32 + kg * 8);
            f16x8 a[4], ev[4];
#pragma unroll
            for (int i = 0; i < 4; ++i) {
                const int cr = wc * 64 + i * 16 + lrow;
                const int cs = (ks * 4 + kg) ^ (cr & 7);
                a[i] = *reinterpret_cast<const f16x8*>(&Glds[cr * 64 + cs * 8]);
            }
#pragma unroll
            for (int j = 0; j < 4; ++j) {
                const int nr = wn * 64 + j * 16 + lrow;
                const int cs = (ks * 4 + kg) ^ (nr & 7);
                ev[j] = *reinterpret_cast<const f16x8*>(&Elds[nr * 64 + cs * 8]) * sv;
            }
#pragma unroll
            for (int i = 0; i < 4; ++i)
#pragma unroll
                for (int j = 0; j < 4; ++j)
                    acc[i][j] = MFMA16(a[i], ev[j], acc[i][j]);
        }
    }

    // store partial: n rows, c cols; j-outer/i-inner for contiguous 64B runs
    f16* pb = partial + ((size_t)bi * 4 + kc) * NPOS * IC;
    const int n0 = nblk * 128 + wn * 64;
    const int c0 = wc * 64;
#pragma unroll
    for (int j = 0; j < 4; ++j) {
        f16* rowp = pb + (size_t)(n0 + j * 16 + lrow) * IC + c0 + kg * 4;
#pragma unroll
        for (int i = 0; i < 4; ++i) {
            f16x4 o = { (f16)acc[i][j][0], (f16)acc[i][j][1],
                        (f16)acc[i][j][2], (f16)acc[i][j][3] };
            *reinterpret_cast<f16x4*>(rowp + i * 16) = o;
        }
    }
}

// ---------------- reduce partials (quad, fp16 in / fp32 accum) -> yT fp16 ----------------
__global__ __launch_bounds__(256) void k_reduce(
    const f16* __restrict__ partial, f16* __restrict__ yT, int b0)
{
    const int bi  = blockIdx.y;
    const int idx = blockIdx.x * 256 + threadIdx.x;   // over NPOS*IC/8
    const f16x8* p = reinterpret_cast<const f16x8*>(partial + (size_t)bi * 4 * NPOS * IC);
    float s[8] = {};
#pragma unroll
    for (int kc = 0; kc < 4; ++kc) {
        f16x8 v = p[(size_t)kc * (NPOS * IC / 8) + idx];
#pragma unroll
        for (int k = 0; k < 8; ++k)
            s[k] += (float)v[k];
    }
    f16x8 o;
#pragma unroll
    for (int k = 0; k < 8; ++k)
        o[k] = (f16)s[k];
    *reinterpret_cast<f16x8*>(yT + (size_t)(b0 + bi) * NPOS * IC + (size_t)idx * 8) = o;
}

// ---------------- final conv + residual: 64x64 per wave ----------------
__global__ __launch_bounds__(256) void k_conv(
    const float* __restrict__ x, const f16* __restrict__ Wc, const float* __restrict__ Wb,
    const f16* __restrict__ yT, float* __restrict__ out)
{
    const int w    = threadIdx.x >> 6;
    const int lane = threadIdx.x & 63;
    const int lrow = lane & 15;
    const int kg   = lane >> 4;
    const int gwid = blockIdx.x * 4 + w;      // 0..2047
    const int ob   = gwid & 3;                // o-block of 64
    const int nb   = (gwid >> 2) & 63;        // n-block of 64
    const int b    = gwid >> 8;
    const int o0   = ob * 64;
    const int n0   = nb * 64;

    const f16* Y = yT + (size_t)b * NPOS * IC;
    f32x4 acc[4][4] = {};
#pragma unroll
    for (int ks = 0; ks < 4; ++ks) {
        const int k = ks * 32 + kg * 8;
        f16x8 a[4], bv[4];
#pragma unroll
        for (int i = 0; i < 4; ++i) {
            a[i]  = *reinterpret_cast<const f16x8*>(Wc + (size_t)(o0 + i * 16 + lrow) * IC + k);
            bv[i] = *reinterpret_cast<const f16x8*>(Y + (size_t)(n0 + i * 16 + lrow) * IC + k);
        }
#pragma unroll
        for (int i = 0; i < 4; ++i)
#pragma unroll
            for (int j = 0; j < 4; ++j)
                acc[i][j] = MFMA16(a[i], bv[j], acc[i][j]);
    }
#pragma unroll
    for (int i = 0; i < 4; ++i) {
        const int o = o0 + i * 16 + kg * 4;
#pragma unroll
        for (int j = 0; j < 4; ++j) {
            const int n = n0 + j * 16 + lrow;
#pragma unroll
            for (int r = 0; r < 4; ++r) {
                const size_t off = ((size_t)b * CIN + o + r) * NPOS + n;
                out[off] = acc[i][j][r] + x[off] + Wb[o + r];
            }
        }
    }
}

extern "C" void kernel_launch(void* const* d_in, const int* in_sizes, int n_in,
                              void* d_out, int out_size, void* d_ws, size_t ws_size,
                              hipStream_t stream)
{
    const float* x  = (const float*)d_in[0];
    const float* gw = (const float*)d_in[1];
    const float* gb = (const float*)d_in[2];
    const float* tw = (const float*)d_in[3];
    const float* tb = (const float*)d_in[4];
    const float* pw = (const float*)d_in[5];
    const float* pb = (const float*)d_in[6];
    const float* Ww = (const float*)d_in[7];
    const float* Wb = (const float*)d_in[8];
    float* out = (float*)d_out;

    char* ws = (char*)d_ws;
    size_t off = 0;
    auto alloc = [&](size_t bytes) -> char* {
        char* p = ws + off;
        off += (bytes + 255) & ~(size_t)255;
        return p;
    };
    f16* xT   = (f16*)alloc((size_t)NB * NPOS * CIN * 2);        // 16.8 MB
    f16* wAll = (f16*)alloc((size_t)384 * 256 * 2);
    f16* Wc   = (f16*)alloc((size_t)CIN * IC * 2);
    f16* th   = (f16*)alloc((size_t)NB * NPOS * IC * 2);         // 8.4 MB
    f16* ph   = (f16*)alloc((size_t)NB * NPOS * IC * 2);
    f16* gT   = (f16*)alloc((size_t)NB * NPOS * IC * 2);
    f16* Ep   = (f16*)alloc((size_t)4 * NPOS * NPOS * 2);        // 134 MB (quad)
    float* lmax = (float*)alloc((size_t)4 * 64 * NPOS * 4);      // 4.2 MB
    float* lsum = (float*)alloc((size_t)4 * 64 * NPOS * 4);
    f16* sca  = (f16*)alloc((size_t)4 * 64 * NPOS * 2);          // 2.1 MB
    f16* gs   = (f16*)alloc((size_t)4 * IC * NPOS * 2);          // 4.2 MB
    f16* partial = (f16*)alloc((size_t)4 * 4 * NPOS * IC * 2);   // 16.8 MB (quad)
    f16* yT   = (f16*)alloc((size_t)NB * NPOS * IC * 2);         // 8.4 MB

    k_prep_w<<<128, 256, 0, stream>>>(gw, tw, pw, Ww, wAll, Wc);
    k_split_x<<<dim3(64, 4, 8), 256, 0, stream>>>(x, xT);
    k_proj<<<dim3(16, 6, 8), 256, 0, stream>>>(xT, wAll, gb, tb, pb, th, ph, gT);

    for (int b0 = 0; b0 < NB; b0 += 4) {
        k_gemm1<<<4096, 256, 0, stream>>>(th, ph, Ep, lmax, lsum, b0);
        k_prep<<<dim3(16, 4), 256, 0, stream>>>(lmax, lsum, gT, sca, gs, b0);
        k_gemm2<<<512, 256, 0, stream>>>(Ep, sca, gs, partial);
        k_reduce<<<dim3(256, 4), 256, 0, stream>>>(partial, yT, b0);
    }
    k_conv<<<dim3(512), 256, 0, stream>>>(x, Wc, Wb, yT, out);
}

// Round 16
// 328.093 us; speedup vs baseline: 1.4295x; 1.0453x over previous
//
#include <hip/hip_runtime.h>
#include <hip/hip_bf16.h>

// NonLocalBlock2D: x[8,256,64,64] fp32
// All-fp16 pipeline, batches in QUADS. gemm1 AND gemm2 are LDS-staged
// 128x128-block GEMMs, XOR-swizzled, conflict-free ds_read_b128, with
// REGISTER-PREFETCH software pipelining (loads in flight across barriers).
//   k_prep_w  : weights -> wAll fp16 [384][256], Wc fp16 [256][128]
//   k_split_x : transpose x -> xT fp16 [b][n][c]
//   k_proj    : fp16 GEMM 64x64/wave -> th/ph fp16 [b][n][c], gT fp16 [b][c][n]
//   k_gemm1   : E'[bi][n][m] = exp(theta·phi - lmax[rb][m]); lmax/lsum[64][m]
//   k_prep    : cmax/ssum from lmax/lsum; sca[bi][rb][m] fp16; gs fp16 = g*rcp
//   k_gemm2   : 2-deep pipelined: partial[bi][kc][n][c] (fp16) = sum_m gs·(E'*sca)
//   k_reduce  : yT[b][n][c] fp16 = sum_kc partial (fp32 accum)
//   k_conv    : out = Wc·yT + Wb + x   (at HBM BW ceiling)

#define IC   128
#define CIN  256
#define NPOS 4096
#define NB   8

typedef _Float16 f16;
typedef __attribute__((ext_vector_type(8))) _Float16 f16x8;
typedef __attribute__((ext_vector_type(4))) _Float16 f16x4;
typedef __attribute__((ext_vector_type(4))) float f32x4;
typedef __attribute__((ext_vector_type(4))) float fvec4;

#define MFMA16(a, b, c) __builtin_amdgcn_mfma_f32_16x16x32_f16((a), (b), (c), 0, 0, 0)

// ---------------- weight prep: wAll fp16 [384][256], Wc fp16 [256][128] ----------------
__global__ __launch_bounds__(256) void k_prep_w(
    const float* __restrict__ gw, const float* __restrict__ tw, const float* __restrict__ pw,
    const float* __restrict__ Ww, f16* __restrict__ wAll, f16* __restrict__ Wc)
{
    const int idx = (blockIdx.x * 256 + threadIdx.x) * 4;
    if (idx < 384 * 256) {
        const int row = idx >> 8, col = idx & 255;
        const float* src = (row < 128) ? (gw + row * 256)
                         : (row < 256) ? (tw + (row - 128) * 256)
                                       : (pw + (row - 256) * 256);
        fvec4 v = *reinterpret_cast<const fvec4*>(src + col);
        f16x4 o = { (f16)v[0], (f16)v[1], (f16)v[2], (f16)v[3] };
        *reinterpret_cast<f16x4*>(wAll + idx) = o;
    } else {
        const int j = idx - 384 * 256;          // over 256*128
        fvec4 v = *reinterpret_cast<const fvec4*>(Ww + j);
        f16x4 o = { (f16)v[0], (f16)v[1], (f16)v[2], (f16)v[3] };
        *reinterpret_cast<f16x4*>(Wc + j) = o;
    }
}

// ---------------- transpose x: [b][c][n] fp32 -> [b][n][c] fp16 ----------------
__global__ __launch_bounds__(256) void k_split_x(
    const float* __restrict__ x, f16* __restrict__ xT)
{
    __shared__ float tile[64][65];
    const int b  = blockIdx.z;
    const int c0 = blockIdx.y * 64;
    const int n0 = blockIdx.x * 64;
    const int t  = threadIdx.x;
    {
        const int cc = t >> 4, nn = (t & 15) * 4;
        const float* src = x + ((size_t)b * CIN + c0) * NPOS + n0;
#pragma unroll
        for (int p = 0; p < 4; ++p) {
            fvec4 v = *reinterpret_cast<const fvec4*>(src + (size_t)(cc + p * 16) * NPOS + nn);
            tile[cc + p * 16][nn + 0] = v[0];
            tile[cc + p * 16][nn + 1] = v[1];
            tile[cc + p * 16][nn + 2] = v[2];
            tile[cc + p * 16][nn + 3] = v[3];
        }
    }
    __syncthreads();
    {
        const int c4 = (t & 15) * 4, nr = t >> 4;
#pragma unroll
        for (int p = 0; p < 4; ++p) {
            const int n = nr + p * 16;
            f16x4 o = { (f16)tile[c4 + 0][n], (f16)tile[c4 + 1][n],
                        (f16)tile[c4 + 2][n], (f16)tile[c4 + 3][n] };
            *reinterpret_cast<f16x4*>(xT + ((size_t)b * NPOS + n0 + n) * CIN + c0 + c4) = o;
        }
    }
}

// ---------------- projections: fp16 GEMM, 64x64 per wave ----------------
__global__ __launch_bounds__(256) void k_proj(
    const f16* __restrict__ xT, const f16* __restrict__ wAll,
    const float* __restrict__ gb, const float* __restrict__ tb, const float* __restrict__ pb,
    f16* __restrict__ th, f16* __restrict__ ph, f16* __restrict__ gT)
{
    const int w    = threadIdx.x >> 6;
    const int lane = threadIdx.x & 63;
    const int lrow = lane & 15;
    const int kg   = lane >> 4;
    const int b    = blockIdx.z;
    const int c0   = blockIdx.y * 64;              // [0,384)
    const int n0   = blockIdx.x * 256 + w * 64;

    const f16* X = xT + (size_t)b * NPOS * CIN;

    f32x4 acc[4][4] = {};
#pragma unroll
    for (int ks = 0; ks < 8; ++ks) {
        const int k = ks * 32 + kg * 8;
        f16x8 a[4], bv[4];
#pragma unroll
        for (int i = 0; i < 4; ++i) {
            a[i]  = *reinterpret_cast<const f16x8*>(wAll + (size_t)(c0 + i * 16 + lrow) * CIN + k);
            bv[i] = *reinterpret_cast<const f16x8*>(X + (size_t)(n0 + i * 16 + lrow) * CIN + k);
        }
#pragma unroll
        for (int i = 0; i < 4; ++i)
#pragma unroll
            for (int j = 0; j < 4; ++j)
                acc[i][j] = MFMA16(a[i], bv[j], acc[i][j]);
    }
    const int set = c0 >> 7;                 // 0:g 1:theta 2:phi
    if (set == 0) {
#pragma unroll
        for (int i = 0; i < 4; ++i) {
            const int c = c0 + i * 16 + kg * 4;
#pragma unroll
            for (int j = 0; j < 4; ++j) {
                const int n = n0 + j * 16 + lrow;
#pragma unroll
                for (int r = 0; r < 4; ++r)
                    gT[((size_t)b * IC + c + r) * NPOS + n] = (f16)(acc[i][j][r] + gb[c + r]);
            }
        }
    } else {
        const float* Bi = (set == 1) ? tb : pb;
        f16* dst = (set == 1) ? th : ph;
        const int cl0 = (c0 & 127);
#pragma unroll
        for (int i = 0; i < 4; ++i) {
            const int c = cl0 + i * 16 + kg * 4;
#pragma unroll
            for (int j = 0; j < 4; ++j) {
                const int n = n0 + j * 16 + lrow;
                f16x4 o = { (f16)(acc[i][j][0] + Bi[c + 0]), (f16)(acc[i][j][1] + Bi[c + 1]),
                            (f16)(acc[i][j][2] + Bi[c + 2]), (f16)(acc[i][j][3] + Bi[c + 3]) };
                *reinterpret_cast<f16x4*>(dst + ((size_t)b * NPOS + n) * IC + c) = o;
            }
        }
    }
}

// ---- GEMM1 (quad): LDS-staged 128x128 block, K-split halves (32KB LDS),
//      register-prefetch of half 1 in flight across barrier + MFMA(h0). ----
__global__ __launch_bounds__(256, 4) void k_gemm1(
    const f16* __restrict__ th, const f16* __restrict__ ph,
    f16* __restrict__ Ep, float* __restrict__ lmax, float* __restrict__ lsum, int b0)
{
    __shared__ f16 Alds[128 * 64];    // phi tile, one K-half
    __shared__ f16 Blds[128 * 64];    // theta tile, one K-half
    const int t    = threadIdx.x;
    const int w    = t >> 6;
    const int lane = t & 63;
    const int lrow = lane & 15;
    const int kg   = lane >> 4;
    const int wm   = w & 1;
    const int wn   = w >> 1;
    const int bi   = blockIdx.x >> 10;        // 0..3
    const int rest = blockIdx.x & 1023;
    const int mblk = rest & 31;
    const int nblk = rest >> 5;

    const f16* Ag = ph + (size_t)(b0 + bi) * NPOS * IC + (size_t)(mblk * 128) * IC;
    const f16* Bg = th + (size_t)(b0 + bi) * NPOS * IC + (size_t)(nblk * 128) * IC;

    const int trow = t >> 3;                  // 0..31
    const int tc   = t & 7;                   // 16B chunk 0..7

    // load h0 into regs
    f16x8 pa[4], pb[4];
#pragma unroll
    for (int it = 0; it < 4; ++it) {
        const int row = trow + it * 32;
        pa[it] = *reinterpret_cast<const f16x8*>(Ag + (size_t)row * IC + tc * 8);
        pb[it] = *reinterpret_cast<const f16x8*>(Bg + (size_t)row * IC + tc * 8);
    }
    // write h0 to LDS (swizzled)
#pragma unroll
    for (int it = 0; it < 4; ++it) {
        const int row = trow + it * 32;
        const int cs  = tc ^ (row & 7);
        *reinterpret_cast<f16x8*>(&Alds[row * 64 + cs * 8]) = pa[it];
        *reinterpret_cast<f16x8*>(&Blds[row * 64 + cs * 8]) = pb[it];
    }
    // prefetch h1 — stays in flight across the barrier and MFMA(h0)
#pragma unroll
    for (int it = 0; it < 4; ++it) {
        const int row = trow + it * 32;
        pa[it] = *reinterpret_cast<const f16x8*>(Ag + (size_t)row * IC + 64 + tc * 8);
        pb[it] = *reinterpret_cast<const f16x8*>(Bg + (size_t)row * IC + 64 + tc * 8);
    }
    __syncthreads();

    f32x4 acc[4][4] = {};
#pragma unroll
    for (int ks = 0; ks < 2; ++ks) {
        f16x8 a[4], bv[4];
#pragma unroll
        for (int i = 0; i < 4; ++i) {
            const int mr = wm * 64 + i * 16 + lrow;
            const int cs = (ks * 4 + kg) ^ (mr & 7);
            a[i] = *reinterpret_cast<const f16x8*>(&Alds[mr * 64 + cs * 8]);
        }
#pragma unroll
        for (int j = 0; j < 4; ++j) {
            const int nr = wn * 64 + j * 16 + lrow;
            const int cs = (ks * 4 + kg) ^ (nr & 7);
            bv[j] = *reinterpret_cast<const f16x8*>(&Blds[nr * 64 + cs * 8]);
        }
#pragma unroll
        for (int i = 0; i < 4; ++i)
#pragma unroll
            for (int j = 0; j < 4; ++j)
                acc[i][j] = MFMA16(a[i], bv[j], acc[i][j]);
    }
    __syncthreads();
    // write h1 to LDS
#pragma unroll
    for (int it = 0; it < 4; ++it) {
        const int row = trow + it * 32;
        const int cs  = tc ^ (row & 7);
        *reinterpret_cast<f16x8*>(&Alds[row * 64 + cs * 8]) = pa[it];
        *reinterpret_cast<f16x8*>(&Blds[row * 64 + cs * 8]) = pb[it];
    }
    __syncthreads();
#pragma unroll
    for (int ks = 0; ks < 2; ++ks) {
        f16x8 a[4], bv[4];
#pragma unroll
        for (int i = 0; i < 4; ++i) {
            const int mr = wm * 64 + i * 16 + lrow;
            const int cs = (ks * 4 + kg) ^ (mr & 7);
            a[i] = *reinterpret_cast<const f16x8*>(&Alds[mr * 64 + cs * 8]);
        }
#pragma unroll
        for (int j = 0; j < 4; ++j) {
            const int nr = wn * 64 + j * 16 + lrow;
            const int cs = (ks * 4 + kg) ^ (nr & 7);
            bv[j] = *reinterpret_cast<const f16x8*>(&Blds[nr * 64 + cs * 8]);
        }
#pragma unroll
        for (int i = 0; i < 4; ++i)
#pragma unroll
            for (int j = 0; j < 4; ++j)
                acc[i][j] = MFMA16(a[i], bv[j], acc[i][j]);
    }

    const int m0 = mblk * 128 + wm * 64;
    const int n0 = nblk * 128 + wn * 64;
    f16* eb = Ep + (size_t)bi * NPOS * NPOS;
    const float L2E = 1.4426950408889634f;

    // pass A: per-m column max over this wave's 64 n
    f32x4 cm[4], ncml[4];
#pragma unroll
    for (int i = 0; i < 4; ++i)
#pragma unroll
        for (int r = 0; r < 4; ++r) {
            float c = fmaxf(fmaxf(acc[i][0][r], acc[i][1][r]),
                            fmaxf(acc[i][2][r], acc[i][3][r]));
            c = fmaxf(c, __shfl_xor(c, 1));
            c = fmaxf(c, __shfl_xor(c, 2));
            c = fmaxf(c, __shfl_xor(c, 4));
            c = fmaxf(c, __shfl_xor(c, 8));
            cm[i][r] = c;
            ncml[i][r] = -c * L2E;
        }

    // pass B: j-outer / i-inner — line-coalesced stores + running sums
    f32x4 s[4] = {};
#pragma unroll
    for (int j = 0; j < 4; ++j) {
        f16* rowp = eb + (size_t)(n0 + j * 16 + lrow) * NPOS + m0 + kg * 4;
#pragma unroll
        for (int i = 0; i < 4; ++i) {
            f16x4 ev;
#pragma unroll
            for (int r = 0; r < 4; ++r) {
                float e = exp2f(__builtin_fmaf(acc[i][j][r], L2E, ncml[i][r]));
                s[i][r] += e;
                ev[r] = (f16)e;
            }
            *reinterpret_cast<f16x4*>(rowp + i * 16) = ev;
        }
    }

    // stats out (64-row slots)
    const int rowblk = nblk * 2 + wn;         // 0..63
#pragma unroll
    for (int i = 0; i < 4; ++i)
#pragma unroll
        for (int r = 0; r < 4; ++r) {
            float ss = s[i][r];
            ss += __shfl_xor(ss, 1);
            ss += __shfl_xor(ss, 2);
            ss += __shfl_xor(ss, 4);
            ss += __shfl_xor(ss, 8);
            if (lrow == 0) {
                const size_t off = ((size_t)bi * 64 + rowblk) * NPOS + m0 + i * 16 + kg * 4 + r;
                lmax[off] = cm[i][r];
                lsum[off] = ss;
            }
        }
}

// ---- prep (quad): cmax/ssum over 64 slots; sca fp16; gs = g/ssum ----
__global__ __launch_bounds__(256) void k_prep(
    const float* __restrict__ lmax, const float* __restrict__ lsum,
    const f16* __restrict__ gT, f16* __restrict__ sca, f16* __restrict__ gs, int b0)
{
    const int bi = blockIdx.y;
    const int m  = blockIdx.x * 256 + threadIdx.x;
    const float* lm = lmax + (size_t)bi * 64 * NPOS;
    const float* ls = lsum + (size_t)bi * 64 * NPOS;
    float cm = -3.0e38f;
#pragma unroll 8
    for (int rb = 0; rb < 64; ++rb)
        cm = fmaxf(cm, lm[(size_t)rb * NPOS + m]);
    float s = 0.f;
    f16* scab = sca + (size_t)bi * 64 * NPOS;
#pragma unroll 8
    for (int rb = 0; rb < 64; ++rb) {
        float e = __expf(lm[(size_t)rb * NPOS + m] - cm);
        s += e * ls[(size_t)rb * NPOS + m];
        scab[(size_t)rb * NPOS + m] = (f16)e;
    }
    const float rc = 1.0f / s;
    const f16* gb = gT + (size_t)(b0 + bi) * IC * NPOS;
    f16* gsb = gs + (size_t)bi * IC * NPOS;
#pragma unroll 8
    for (int c = 0; c < IC; ++c)
        gsb[(size_t)c * NPOS + m] = (f16)((float)gb[(size_t)c * NPOS + m] * rc);
}

// ---- GEMM2 (quad): LDS-staged 128c x 128n block, 64-m sub-chunks,
//      2-deep double-buffered pipeline: ONE barrier per sub-chunk, next
//      sub-chunk's loads in flight across barrier + MFMA. ----
__global__ __launch_bounds__(256, 2) void k_gemm2(
    const f16* __restrict__ Ep, const f16* __restrict__ sca,
    const f16* __restrict__ gs, f16* __restrict__ partial)
{
    __shared__ f16 Elds[2][128 * 64];   // E' tile (n rows), double-buffered
    __shared__ f16 Glds[2][128 * 64];   // gs tile (c rows)
    const int t    = threadIdx.x;
    const int w    = t >> 6;
    const int lane = t & 63;
    const int lrow = lane & 15;
    const int kg   = lane >> 4;
    const int wc   = w & 1;
    const int wn   = w >> 1;
    const int bi   = blockIdx.x >> 7;         // 0..3
    const int rest = blockIdx.x & 127;
    const int kc   = rest & 3;                // m-chunk of 1024
    const int nblk = rest >> 2;               // 0..31, n-block of 128

    const f16* Eg  = Ep + (size_t)bi * NPOS * NPOS + (size_t)(nblk * 128) * NPOS + kc * 1024;
    const f16* Gg  = gs + (size_t)bi * IC * NPOS + kc * 1024;
    const int  rb  = nblk * 2 + wn;           // wave's 64-row stats slot
    const f16* srow = sca + ((size_t)bi * 64 + rb) * NPOS + kc * 1024;

    const int trow = t >> 3;                  // 0..31
    const int tc   = t & 7;                   // 16B chunk 0..7

    // prefetch sub-chunk 0
    f16x8 pe[4], pg[4];
#pragma unroll
    for (int it = 0; it < 4; ++it) {
        const int row = trow + it * 32;
        pe[it] = *reinterpret_cast<const f16x8*>(Eg + (size_t)row * NPOS + tc * 8);
        pg[it] = *reinterpret_cast<const f16x8*>(Gg + (size_t)row * NPOS + tc * 8);
    }

    f32x4 acc[4][4] = {};
    for (int sc = 0; sc < 16; ++sc) {         // 16 sub-chunks of 64 m
        const int cur = sc & 1;
        // write staged regs to LDS (swizzled)
#pragma unroll
        for (int it = 0; it < 4; ++it) {
            const int row = trow + it * 32;
            const int cs  = tc ^ (row & 7);
            *reinterpret_cast<f16x8*>(&Elds[cur][row * 64 + cs * 8]) = pe[it];
            *reinterpret_cast<f16x8*>(&Glds[cur][row * 64 + cs * 8]) = pg[it];
        }
        // issue next sub-chunk's loads — in flight across barrier + MFMA
        if (sc < 15) {
#pragma unroll
            for (int it = 0; it < 4; ++it) {
                const int row = trow + it * 32;
                pe[it] = *reinterpret_cast<const f16x8*>(Eg + (size_t)row * NPOS + (sc + 1) * 64 + tc * 8);
                pg[it] = *reinterpret_cast<const f16x8*>(Gg + (size_t)row * NPOS + (sc + 1) * 64 + tc * 8);
            }
        }
        __syncthreads();

#pragma unroll
        for (int ks = 0; ks < 2; ++ks) {
            f16x8 sv = *reinterpret_cast<const f16x8*>(srow + sc * 64 + ks * 32 + kg * 8);
            f16x8 a[4], ev[4];
#pragma unroll
            for (int i = 0; i < 4; ++i) {
                const int cr = wc * 64 + i * 16 + lrow;
                const int cs = (ks * 4 + kg) ^ (cr & 7);
                a[i] = *reinterpret_cast<const f16x8*>(&Glds[cur][cr * 64 + cs * 8]);
            }
#pragma unroll
            for (int j = 0; j < 4; ++j) {
                const int nr = wn * 64 + j * 16 + lrow;
                const int cs = (ks * 4 + kg) ^ (nr & 7);
                ev[j] = *reinterpret_cast<const f16x8*>(&Elds[cur][nr * 64 + cs * 8]) * sv;
            }
#pragma unroll
            for (int i = 0; i < 4; ++i)
#pragma unroll
                for (int j = 0; j < 4; ++j)
                    acc[i][j] = MFMA16(a[i], ev[j], acc[i][j]);
        }
        // no trailing barrier: next iter writes buf[cur^1]; buf[cur] is only
        // rewritten at sc+2, separated from this iter's reads by sc+1's barrier
    }

    // store partial: n rows, c cols; j-outer/i-inner for contiguous 64B runs
    f16* pb = partial + ((size_t)bi * 4 + kc) * NPOS * IC;
    const int n0 = nblk * 128 + wn * 64;
    const int c0 = wc * 64;
#pragma unroll
    for (int j = 0; j < 4; ++j) {
        f16* rowp = pb + (size_t)(n0 + j * 16 + lrow) * IC + c0 + kg * 4;
#pragma unroll
        for (int i = 0; i < 4; ++i) {
            f16x4 o = { (f16)acc[i][j][0], (f16)acc[i][j][1],
                        (f16)acc[i][j][2], (f16)acc[i][j][3] };
            *reinterpret_cast<f16x4*>(rowp + i * 16) = o;
        }
    }
}

// ---------------- reduce partials (quad, fp16 in / fp32 accum) -> yT fp16 ----------------
__global__ __launch_bounds__(256) void k_reduce(
    const f16* __restrict__ partial, f16* __restrict__ yT, int b0)
{
    const int bi  = blockIdx.y;
    const int idx = blockIdx.x * 256 + threadIdx.x;   // over NPOS*IC/8
    const f16x8* p = reinterpret_cast<const f16x8*>(partial + (size_t)bi * 4 * NPOS * IC);
    float s[8] = {};
#pragma unroll
    for (int kc = 0; kc < 4; ++kc) {
        f16x8 v = p[(size_t)kc * (NPOS * IC / 8) + idx];
#pragma unroll
        for (int k = 0; k < 8; ++k)
            s[k] += (float)v[k];
    }
    f16x8 o;
#pragma unroll
    for (int k = 0; k < 8; ++k)
        o[k] = (f16)s[k];
    *reinterpret_cast<f16x8*>(yT + (size_t)(b0 + bi) * NPOS * IC + (size_t)idx * 8) = o;
}

// ---------------- final conv + residual: 64x64 per wave ----------------
__global__ __launch_bounds__(256) void k_conv(
    const float* __restrict__ x, const f16* __restrict__ Wc, const float* __restrict__ Wb,
    const f16* __restrict__ yT, float* __restrict__ out)
{
    const int w    = threadIdx.x >> 6;
    const int lane = threadIdx.x & 63;
    const int lrow = lane & 15;
    const int kg   = lane >> 4;
    const int gwid = blockIdx.x * 4 + w;      // 0..2047
    const int ob   = gwid & 3;                // o-block of 64
    const int nb   = (gwid >> 2) & 63;        // n-block of 64
    const int b    = gwid >> 8;
    const int o0   = ob * 64;
    const int n0   = nb * 64;

    const f16* Y = yT + (size_t)b * NPOS * IC;
    f32x4 acc[4][4] = {};
#pragma unroll
    for (int ks = 0; ks < 4; ++ks) {
        const int k = ks * 32 + kg * 8;
        f16x8 a[4], bv[4];
#pragma unroll
        for (int i = 0; i < 4; ++i) {
            a[i]  = *reinterpret_cast<const f16x8*>(Wc + (size_t)(o0 + i * 16 + lrow) * IC + k);
            bv[i] = *reinterpret_cast<const f16x8*>(Y + (size_t)(n0 + i * 16 + lrow) * IC + k);
        }
#pragma unroll
        for (int i = 0; i < 4; ++i)
#pragma unroll
            for (int j = 0; j < 4; ++j)
                acc[i][j] = MFMA16(a[i], bv[j], acc[i][j]);
    }
#pragma unroll
    for (int i = 0; i < 4; ++i) {
        const int o = o0 + i * 16 + kg * 4;
#pragma unroll
        for (int j = 0; j < 4; ++j) {
            const int n = n0 + j * 16 + lrow;
#pragma unroll
            for (int r = 0; r < 4; ++r) {
                const size_t off = ((size_t)b * CIN + o + r) * NPOS + n;
                out[off] = acc[i][j][r] + x[off] + Wb[o + r];
            }
        }
    }
}

extern "C" void kernel_launch(void* const* d_in, const int* in_sizes, int n_in,
                              void* d_out, int out_size, void* d_ws, size_t ws_size,
                              hipStream_t stream)
{
    const float* x  = (const float*)d_in[0];
    const float* gw = (const float*)d_in[1];
    const float* gb = (const float*)d_in[2];
    const float* tw = (const float*)d_in[3];
    const float* tb = (const float*)d_in[4];
    const float* pw = (const float*)d_in[5];
    const float* pb = (const float*)d_in[6];
    const float* Ww = (const float*)d_in[7];
    const float* Wb = (const float*)d_in[8];
    float* out = (float*)d_out;

    char* ws = (char*)d_ws;
    size_t off = 0;
    auto alloc = [&](size_t bytes) -> char* {
        char* p = ws + off;
        off += (bytes + 255) & ~(size_t)255;
        return p;
    };
    f16* xT   = (f16*)alloc((size_t)NB * NPOS * CIN * 2);        // 16.8 MB
    f16* wAll = (f16*)alloc((size_t)384 * 256 * 2);
    f16* Wc   = (f16*)alloc((size_t)CIN * IC * 2);
    f16* th   = (f16*)alloc((size_t)NB * NPOS * IC * 2);         // 8.4 MB
    f16* ph   = (f16*)alloc((size_t)NB * NPOS * IC * 2);
    f16* gT   = (f16*)alloc((size_t)NB * NPOS * IC * 2);
    f16* Ep   = (f16*)alloc((size_t)4 * NPOS * NPOS * 2);        // 134 MB (quad)
    float* lmax = (float*)alloc((size_t)4 * 64 * NPOS * 4);      // 4.2 MB
    float* lsum = (float*)alloc((size_t)4 * 64 * NPOS * 4);
    f16* sca  = (f16*)alloc((size_t)4 * 64 * NPOS * 2);          // 2.1 MB
    f16* gs   = (f16*)alloc((size_t)4 * IC * NPOS * 2);          // 4.2 MB
    f16* partial = (f16*)alloc((size_t)4 * 4 * NPOS * IC * 2);   // 16.8 MB (quad)
    f16* yT   = (f16*)alloc((size_t)NB * NPOS * IC * 2);         // 8.4 MB

    k_prep_w<<<128, 256, 0, stream>>>(gw, tw, pw, Ww, wAll, Wc);
    k_split_x<<<dim3(64, 4, 8), 256, 0, stream>>>(x, xT);
    k_proj<<<dim3(16, 6, 8), 256, 0, stream>>>(xT, wAll, gb, tb, pb, th, ph, gT);

    for (int b0 = 0; b0 < NB; b0 += 4) {
        k_gemm1<<<4096, 256, 0, stream>>>(th, ph, Ep, lmax, lsum, b0);
        k_prep<<<dim3(16, 4), 256, 0, stream>>>(lmax, lsum, gT, sca, gs, b0);
        k_gemm2<<<512, 256, 0, stream>>>(Ep, sca, gs, partial);
        k_reduce<<<dim3(256, 4), 256, 0, stream>>>(partial, yT, b0);
    }
    k_conv<<<dim3(512), 256, 0, stream>>>(x, Wc, Wb, yT, out);
}